// Round 15
// baseline (340.276 us; speedup 1.0000x reference)
//
#include <hip/hip_runtime.h>
#include <hip/hip_bf16.h>
#include <hip/hip_fp16.h>
#include <math.h>

#define NN 100000
#define EE 600000
#define FF 64
#define HH 128
#define CHUNK 1024
#define NCHUNK ((NN + CHUNK - 1) / CHUNK)   // 98
#define NCHUNKS_M (NN / 16)                 // 6250 (exact)
#define PREP_ITEMS (NN * FF / 4 + 49280)

typedef unsigned short u16;
typedef unsigned int u32;
typedef __attribute__((ext_vector_type(8))) short bf16x8;
typedef __attribute__((ext_vector_type(4))) float f32x4;

__device__ __forceinline__ u16 f2bf(float f) {
    __hip_bfloat16 h = __float2bfloat16(f);
    return *(u16*)&h;
}
__device__ __forceinline__ float bf2f(u16 u) {
    unsigned int t = ((unsigned int)u) << 16;
    return *(float*)&t;
}
// meta pack: src in bits [31:15], fp16 weight (sign dropped, w>0) in [14:0]
__device__ __forceinline__ u32 enc_meta(int r, float w) {
    u16 hb = __half_as_ushort(__float2half(w));
    return ((u32)r << 15) | (hb & 0x7fffu);
}
__device__ __forceinline__ void dec_meta(u32 u, int& r, float& w) {
    r = (int)(u >> 15);
    w = __half2float(__ushort_as_half((u16)(u & 0x7fffu)));
}

// ---------------- fused: edge count (atomics) + weight/x prep ----------------

__global__ void build_k(const int* __restrict__ col, int* __restrict__ cnt,
                        const float* __restrict__ W0, const float* __restrict__ W1,
                        const float* __restrict__ W2, const float* __restrict__ Wr,
                        const float* __restrict__ Wg, const float* __restrict__ att_src,
                        const float* __restrict__ att_dst, const float* __restrict__ x,
                        u16* __restrict__ Wt0, u16* __restrict__ Wt1,
                        u16* __restrict__ Wt2, u16* __restrict__ Wtr,
                        float* __restrict__ vs, float* __restrict__ vd,
                        u16* __restrict__ xb) {
    int i = blockIdx.x * 256 + threadIdx.x;
    if (i < EE) {
        atomicAdd(&cnt[col[i]], 1);
        return;
    }
    i -= EE;
    if (i < NN * FF / 4) {          // cast x -> bf16
        float4 v = ((const float4*)x)[i];
        ushort4 o;
        o.x = f2bf(v.x); o.y = f2bf(v.y); o.z = f2bf(v.z); o.w = f2bf(v.w);
        ((ushort4*)xb)[i] = o;
        return;
    }
    i -= NN * FF / 4;
    if (i < 8192) {                 // Wt0: [128][64] from W0[64][128]
        int n = i >> 6, k = i & 63;
        Wt0[i] = f2bf(W0[k * 128 + n]);
        return;
    }
    i -= 8192;
    if (i < 16384) {                // Wt1: [128][128]
        int n = i >> 7, k = i & 127;
        Wt1[i] = f2bf(W1[k * 128 + n]);
        return;
    }
    i -= 16384;
    if (i < 16384) {                // Wt2: [128][128]
        int n = i >> 7, k = i & 127;
        Wt2[i] = f2bf(W2[k * 128 + n]);
        return;
    }
    i -= 16384;
    if (i < 8192) {                 // Wtr: [64][128] from Wr[128][64]
        int n = i >> 7, k = i & 127;
        Wtr[i] = f2bf(Wr[k * 64 + n]);
        return;
    }
    i -= 8192;
    if (i < HH) {                   // gemv: vs/vd = Wg @ att_{src,dst}
        float s1 = 0.f, s2 = 0.f;
        for (int j = 0; j < HH; j++) {
            float w = Wg[i * HH + j];
            s1 += w * att_src[j];
            s2 += w * att_dst[j];
        }
        vs[i] = s1;
        vd[i] = s2;
    }
}

// chunk sums + dinv1 fused
__global__ void chunksum_k(const int* __restrict__ cnt, int* __restrict__ chunk_sum,
                           float* __restrict__ dinv1) {
    int b = blockIdx.x, t = threadIdx.x;
    int base = b * CHUNK + t * 4;
    int s = 0;
    #pragma unroll
    for (int i = 0; i < 4; i++) {
        int idx = base + i;
        if (idx < NN) {
            int cv = cnt[idx];
            s += cv;
            dinv1[idx] = rsqrtf((float)cv + 1.0f);
        }
    }
    __shared__ int sm[4];
    for (int d = 32; d > 0; d >>= 1) s += __shfl_down(s, d);
    if ((t & 63) == 0) sm[t >> 6] = s;
    __syncthreads();
    if (t == 0) chunk_sum[b] = sm[0] + sm[1] + sm[2] + sm[3];
}

// col_ptr + cursor; chunk offset computed in-block (98 serial adds)
__global__ void colptr_k(const int* __restrict__ cnt, const int* __restrict__ chunk_sum,
                         int* __restrict__ col_ptr, int* __restrict__ cursor) {
    int b = blockIdx.x, t = threadIdx.x;
    __shared__ int base_off;
    if (t == 0) {
        int run = 0;
        for (int i = 0; i < b; i++) run += chunk_sum[i];
        base_off = run;
        if (b == 0) col_ptr[NN] = EE;
    }
    int base = b * CHUNK + t * 4;
    int c[4]; int tot = 0;
    #pragma unroll
    for (int i = 0; i < 4; i++) { int idx = base + i; c[i] = (idx < NN) ? cnt[idx] : 0; tot += c[i]; }
    __shared__ int s[256];
    s[t] = tot;
    __syncthreads();
    for (int d = 1; d < 256; d <<= 1) {
        int v = (t >= d) ? s[t - d] : 0;
        __syncthreads();
        s[t] += v;
        __syncthreads();
    }
    int excl = s[t] - tot;
    int off = base_off + excl;
    int pre = 0;
    #pragma unroll
    for (int i = 0; i < 4; i++) {
        int idx = base + i;
        if (idx < NN) {
            col_ptr[idx] = off + pre;
            cursor[idx] = off + pre;
        }
        pre += c[i];
    }
}

// fill CSR: single 4B scatter meta1 = enc(src, dinv1[r]*dinv1[c])
__global__ void fill_k(const int* __restrict__ row, const int* __restrict__ col,
                       int* __restrict__ cursor, const float* __restrict__ dinv1,
                       u32* __restrict__ meta1) {
    int e = blockIdx.x * 256 + threadIdx.x;
    if (e < EE) {
        int r = row[e], c = col[e];
        int slot = atomicAdd(&cursor[c], 1);
        meta1[slot] = enc_meta(r, dinv1[r] * dinv1[c]);
    }
}

// ---------------- layer-1 aggregate: 2 nodes/wave, 4 groups x 8 lanes x 2 streams ----------------

__global__ __launch_bounds__(256, 8) void aggx_k(
    const u16* __restrict__ xb, const int* __restrict__ col_ptr, const u32* __restrict__ meta1,
    const float* __restrict__ dinv1, u16* __restrict__ xout) {
    int wid = threadIdx.x >> 6, lane = threadIdx.x & 63;
    int sub = lane >> 5;
    int c = blockIdx.x * 8 + wid * 2 + sub;
    int hl = lane & 31;
    int g = hl >> 3;             // group 0..3
    int ch = (hl & 7) << 3;      // channel base 0,8,...,56
    int beg = col_ptr[c], end = col_ptr[c + 1];
    float acc[8] = {};

    int pA = beg + g, pB = pA + 4;
    int rA = 0, rB = 0; float wA = 0.f, wB = 0.f;
    if (pA < end) dec_meta(meta1[pA], rA, wA);
    if (pB < end) dec_meta(meta1[pB], rB, wB);
    while (pA < end) {
        bool hb = pB < end;
        bf16x8 vA = *(const bf16x8*)&xb[(size_t)rA * FF + ch];
        bf16x8 vB;
        if (hb) vB = *(const bf16x8*)&xb[(size_t)rB * FF + ch];
        int pA2 = pA + 8, pB2 = pB + 8;
        int rA2 = 0, rB2 = 0; float wA2 = 0.f, wB2 = 0.f;
        if (pA2 < end) dec_meta(meta1[pA2], rA2, wA2);
        if (pB2 < end) dec_meta(meta1[pB2], rB2, wB2);
        #pragma unroll
        for (int j = 0; j < 8; j++) acc[j] = fmaf(bf2f((u16)vA[j]), wA, acc[j]);
        if (hb) {
            #pragma unroll
            for (int j = 0; j < 8; j++) acc[j] = fmaf(bf2f((u16)vB[j]), wB, acc[j]);
        }
        pA = pA2; pB = pB2; rA = rA2; rB = rB2; wA = wA2; wB = wB2;
    }
    // combine 4 groups within half-wave (xor 8, 16)
    #pragma unroll
    for (int j = 0; j < 8; j++) {
        acc[j] += __shfl_xor(acc[j], 8);
        acc[j] += __shfl_xor(acc[j], 16);
    }

    if (g == 0) {
        bf16x8 v = *(const bf16x8*)&xb[(size_t)c * FF + ch];
        float dc = dinv1[c];
        float ws = dc * dc;
        bf16x8 o;
        #pragma unroll
        for (int j = 0; j < 8; j++) {
            float t = fmaf(bf2f((u16)v[j]), ws, acc[j]);
            o[j] = (short)f2bf(t);
        }
        *(bf16x8*)&xout[(size_t)c * FF + ch] = o;
    }
}

// ---------------- GEMM1 fused: y1 = (relu(xagg@W0+b0)) @ W1, plus a_s/a_d ----------------

__global__ __launch_bounds__(256) void gemm1_k(const u16* __restrict__ A,
                                               const u16* __restrict__ Wt0,
                                               const u16* __restrict__ Wt1,
                                               const float* __restrict__ bias,
                                               const float* __restrict__ vs, const float* __restrict__ vd,
                                               u16* __restrict__ Y, float* __restrict__ a_s,
                                               float* __restrict__ a_d) {
    constexpr int K = FF, N = HH, KK = K / 32, NT = N / 16, KK2 = HH / 32;
    constexpr int LSTRIDE = 136;
    __shared__ u16 lds[4][16 * LSTRIDE];
    int lane = threadIdx.x & 63, wid = threadIdx.x >> 6;
    int l15 = lane & 15, l4 = lane >> 4;
    int wg = blockIdx.x * 4 + wid;
    int nwaves = gridDim.x * 4;
    u16* myl = &lds[wid][0];

    bf16x8 a_frag[KK][NT];   // W0t fragments resident
    #pragma unroll
    for (int kk = 0; kk < KK; kk++)
        #pragma unroll
        for (int nt = 0; nt < NT; nt++)
            a_frag[kk][nt] = *(const bf16x8*)&Wt0[(size_t)(nt * 16 + l15) * K + kk * 32 + l4 * 8];

    for (int ch = wg; ch < NCHUNKS_M; ch += nwaves) {
        int row = ch * 16 + l15;
        bf16x8 b_frag[KK];
        #pragma unroll
        for (int kk = 0; kk < KK; kk++)
            b_frag[kk] = *(const bf16x8*)&A[(size_t)row * K + kk * 32 + l4 * 8];
        f32x4 acc[NT] = {};
        #pragma unroll
        for (int kk = 0; kk < KK; kk++)
            #pragma unroll
            for (int nt = 0; nt < NT; nt++)
                acc[nt] = __builtin_amdgcn_mfma_f32_16x16x32_bf16(a_frag[kk][nt], b_frag[kk],
                                                                  acc[nt], 0, 0, 0);
        float s1 = 0.f, s2 = 0.f;
        #pragma unroll
        for (int nt = 0; nt < NT; nt++) {
            f32x4 b4 = *(const f32x4*)&bias[nt * 16 + l4 * 4];
            f32x4 v4 = *(const f32x4*)&vs[nt * 16 + l4 * 4];
            f32x4 d4 = *(const f32x4*)&vd[nt * 16 + l4 * 4];
            float o0 = fmaxf(acc[nt][0] + b4[0], 0.f);
            float o1 = fmaxf(acc[nt][1] + b4[1], 0.f);
            float o2 = fmaxf(acc[nt][2] + b4[2], 0.f);
            float o3 = fmaxf(acc[nt][3] + b4[3], 0.f);
            ushort4 o;
            o.x = f2bf(o0); o.y = f2bf(o1); o.z = f2bf(o2); o.w = f2bf(o3);
            *(ushort4*)&myl[l15 * LSTRIDE + nt * 16 + l4 * 4] = o;
            s1 += o0 * v4[0] + o1 * v4[1] + o2 * v4[2] + o3 * v4[3];
            s2 += o0 * d4[0] + o1 * d4[1] + o2 * d4[2] + o3 * d4[3];
        }
        s1 += __shfl_xor(s1, 16); s1 += __shfl_xor(s1, 32);
        s2 += __shfl_xor(s2, 16); s2 += __shfl_xor(s2, 32);
        if (l4 == 0) {
            a_s[row] = s1;
            a_d[row] = s2;
        }
        // second GEMM: read x1 chunk back as B-fragments, multiply by W1t
        bf16x8 b2[KK2];
        #pragma unroll
        for (int kk2 = 0; kk2 < KK2; kk2++)
            b2[kk2] = *(const bf16x8*)&myl[l15 * LSTRIDE + kk2 * 32 + l4 * 8];
        f32x4 acc2[NT] = {};
        #pragma unroll
        for (int kk2 = 0; kk2 < KK2; kk2++)
            #pragma unroll
            for (int nt = 0; nt < NT; nt++) {
                bf16x8 w1f = *(const bf16x8*)&Wt1[(size_t)(nt * 16 + l15) * HH + kk2 * 32 + l4 * 8];
                acc2[nt] = __builtin_amdgcn_mfma_f32_16x16x32_bf16(w1f, b2[kk2], acc2[nt], 0, 0, 0);
            }
        #pragma unroll
        for (int nt = 0; nt < NT; nt++) {
            ushort4 o;
            o.x = f2bf(acc2[nt][0]);
            o.y = f2bf(acc2[nt][1]);
            o.z = f2bf(acc2[nt][2]);
            o.w = f2bf(acc2[nt][3]);
            *(ushort4*)&Y[(size_t)row * HH + nt * 16 + l4 * 4] = o;
        }
    }
}

// ---------------- attention: 8 lanes per node, online softmax ----------------

__global__ __launch_bounds__(256) void attn_k(const int* __restrict__ col_ptr,
                                              const u32* __restrict__ meta1,
                                              const float* __restrict__ a_s,
                                              const float* __restrict__ a_d,
                                              float* __restrict__ alpha,
                                              float* __restrict__ dinv2) {
    int lane = threadIdx.x & 63, wid = threadIdx.x >> 6;
    int grp = lane >> 3, idx = lane & 7;
    int c = blockIdx.x * 32 + wid * 8 + grp;
    if (c >= NN) return;
    int beg = col_ptr[c], end = col_ptr[c + 1];
    float ad = a_d[c];
    float es = a_s[c] + ad;
    es = (es > 0.f) ? es : 0.2f * es;
    float m = (idx == 0) ? es : -1e30f;
    float s = (idx == 0) ? 1.f : 0.f;
    for (int p = beg + idx; p < end; p += 8) {
        float e = a_s[meta1[p] >> 15] + ad;
        e = (e > 0.f) ? e : 0.2f * e;
        alpha[p] = e;
        float mn = fmaxf(m, e);
        s = s * expf(m - mn) + expf(e - mn);
        m = mn;
    }
    #pragma unroll
    for (int d = 1; d < 8; d <<= 1) {
        float mo = __shfl_xor(m, d);
        float so = __shfl_xor(s, d);
        float mn = fmaxf(m, mo);
        s = s * expf(m - mn) + so * expf(mo - mn);
        m = mn;
    }
    float inv = 1.f / s;
    float aself = expf(es - m) * inv;
    float d2 = rsqrtf(2.f - aself);
    if (idx == 0) dinv2[c] = d2;
    float sc = inv * d2;
    for (int p = beg + idx; p < end; p += 8)
        alpha[p] = expf(alpha[p] - m) * sc;
}

// meta2[p] = enc(src, alpha[p] * dinv2[src])
__global__ void w2_k(const u32* __restrict__ meta1, const float* __restrict__ dinv2,
                     const float* __restrict__ alpha, u32* __restrict__ meta2) {
    int p = blockIdx.x * 256 + threadIdx.x;
    if (p < EE) {
        u32 u = meta1[p];
        int r = (int)(u >> 15);
        float w = alpha[p] * dinv2[r];
        u16 hb = __half_as_ushort(__float2half(w));
        meta2[p] = (u & 0xffff8000u) | (hb & 0x7fffu);
    }
}

// ---------------- fused aggregate + GEMM (256 threads, 16 nodes, 6 streams/node) ----------------
// Phase 1: 16 lanes/node, each lane issues 6 stream-gathers per iteration (6 edges
// in flight per node, stride 6); relu-agg rows land in 16x136 LDS tile.
// Phase 2: wave wid computes n-tiles [wid*NT_W,(wid+1)*NT_W) of 16x128 @ 128xNOUT.

template <int NOUT, bool OUTF32>
__global__ __launch_bounds__(256, 8) void agg_gemm_k(
    const u16* __restrict__ xw, const int* __restrict__ col_ptr, const u32* __restrict__ meta,
    const float* __restrict__ dinv2, const float* __restrict__ bias_in,
    const u16* __restrict__ Wt, const float* __restrict__ bias_out, void* __restrict__ Y_) {
    constexpr int KK2 = HH / 32;        // 4
    constexpr int NT = NOUT / 16;       // 8 or 4
    constexpr int NT_W = NT / 4;        // 2 or 1
    constexpr int NS = 6;               // edge streams per node
    constexpr int LSTRIDE = 136;
    __shared__ u16 lds[16 * LSTRIDE];
    int tid = threadIdx.x;
    int lane = tid & 63, wid = tid >> 6;
    int node = tid >> 4;                // 0..15
    int ch = (tid & 15) << 3;           // channel base 0..120
    int cbase = blockIdx.x * 16;
    int c = cbase + node;
    int beg = col_ptr[c], end = col_ptr[c + 1];
    float acc[8] = {};

    // phase 1: 6 streams, stride 6
    int p[NS]; int r[NS]; float w[NS];
    #pragma unroll
    for (int s = 0; s < NS; s++) {
        p[s] = beg + s; r[s] = 0; w[s] = 0.f;
        if (p[s] < end) dec_meta(meta[p[s]], r[s], w[s]);
    }
    while (p[0] < end) {
        bf16x8 v[NS];
        bool h[NS];
        #pragma unroll
        for (int s = 0; s < NS; s++) {
            h[s] = p[s] < end;
            if (h[s]) v[s] = *(const bf16x8*)&xw[(size_t)r[s] * HH + ch];
        }
        int r2[NS]; float w2[NS];
        #pragma unroll
        for (int s = 0; s < NS; s++) {
            p[s] += NS; r2[s] = 0; w2[s] = 0.f;
            if (p[s] < end) dec_meta(meta[p[s]], r2[s], w2[s]);
        }
        #pragma unroll
        for (int s = 0; s < NS; s++) {
            if (h[s]) {
                #pragma unroll
                for (int j = 0; j < 8; j++) acc[j] = fmaf(bf2f((u16)v[s][j]), w[s], acc[j]);
            }
        }
        #pragma unroll
        for (int s = 0; s < NS; s++) { r[s] = r2[s]; w[s] = w2[s]; }
    }
    {   // self loop + bias_in + relu -> LDS row (bf16)
        bf16x8 v = *(const bf16x8*)&xw[(size_t)c * HH + ch];
        float dc = dinv2[c];
        float ws = dc * dc;
        f32x4 b4a = *(const f32x4*)&bias_in[ch];
        f32x4 b4b = *(const f32x4*)&bias_in[ch + 4];
        bf16x8 o;
        #pragma unroll
        for (int j = 0; j < 8; j++) {
            float bj = (j < 4) ? b4a[j] : b4b[j - 4];
            float t = fmaxf(fmaf(bf2f((u16)v[j]), ws, acc[j]) + bj, 0.f);
            o[j] = (short)f2bf(t);
        }
        *(bf16x8*)&lds[node * LSTRIDE + ch] = o;
    }
    __syncthreads();

    // phase 2: wave wid handles n-tiles [wid*NT_W, (wid+1)*NT_W)
    int l15 = lane & 15, l4 = lane >> 4;
    bf16x8 b2[KK2];
    #pragma unroll
    for (int kk2 = 0; kk2 < KK2; kk2++)
        b2[kk2] = *(const bf16x8*)&lds[l15 * LSTRIDE + kk2 * 32 + l4 * 8];
    int row = cbase + l15;
    #pragma unroll
    for (int ntw = 0; ntw < NT_W; ntw++) {
        int nt = wid * NT_W + ntw;
        f32x4 acc2 = {};
        #pragma unroll
        for (int kk2 = 0; kk2 < KK2; kk2++) {
            bf16x8 wf = *(const bf16x8*)&Wt[(size_t)(nt * 16 + l15) * HH + kk2 * 32 + l4 * 8];
            acc2 = __builtin_amdgcn_mfma_f32_16x16x32_bf16(wf, b2[kk2], acc2, 0, 0, 0);
        }
        int col = nt * 16 + l4 * 4;
        if (OUTF32) {
            float4 o;
            f32x4 bo = *(const f32x4*)&bias_out[col];
            o.x = acc2[0] + bo[0];
            o.y = acc2[1] + bo[1];
            o.z = acc2[2] + bo[2];
            o.w = acc2[3] + bo[3];
            *(float4*)&((float*)Y_)[(size_t)row * NOUT + col] = o;
        } else {
            ushort4 o;
            o.x = f2bf(acc2[0]);
            o.y = f2bf(acc2[1]);
            o.z = f2bf(acc2[2]);
            o.w = f2bf(acc2[3]);
            *(ushort4*)&((u16*)Y_)[(size_t)row * NOUT + col] = o;
        }
    }
}

// ---------------- launch ----------------

extern "C" void kernel_launch(void* const* d_in, const int* in_sizes, int n_in,
                              void* d_out, int out_size, void* d_ws, size_t ws_size,
                              hipStream_t stream) {
    const float* x = (const float*)d_in[0];
    const int* eidx = (const int*)d_in[1];     // [2][E]: row, col
    const float* W0 = (const float*)d_in[3];
    const float* b0 = (const float*)d_in[4];
    const float* Wg = (const float*)d_in[5];
    const float* att_src = (const float*)d_in[6];
    const float* att_dst = (const float*)d_in[7];
    const float* W1 = (const float*)d_in[8];
    const float* b1 = (const float*)d_in[9];
    const float* W2 = (const float*)d_in[10];
    const float* b2 = (const float*)d_in[11];
    const float* Wr = (const float*)d_in[12];
    const float* br = (const float*)d_in[13];
    float* out = (float*)d_out;

    const int* erow = eidx;
    const int* ecol = eidx + EE;

    char* p = (char*)d_ws;
    auto alloc = [&](size_t bytes) {
        void* r = (void*)p;
        p += (bytes + 255) & ~(size_t)255;
        return r;
    };
    int* col_ptr = (int*)alloc((NN + 1) * sizeof(int));
    u32* meta1 = (u32*)alloc(EE * sizeof(u32));
    u32* meta2 = (u32*)alloc(EE * sizeof(u32));
    int* cnt = (int*)alloc(NN * sizeof(int));
    int* cursor = (int*)alloc(NN * sizeof(int));
    int* chunk_sum = (int*)alloc(128 * sizeof(int));
    float* alpha = (float*)alloc(EE * sizeof(float));
    float* dinv1 = (float*)alloc(NN * sizeof(float));
    float* dinv2 = (float*)alloc(NN * sizeof(float));
    float* a_s = (float*)alloc(NN * sizeof(float));
    float* a_d = (float*)alloc(NN * sizeof(float));
    float* vs = (float*)alloc(HH * sizeof(float));
    float* vd = (float*)alloc(HH * sizeof(float));
    u16* Wt0 = (u16*)alloc(8192 * sizeof(u16));    // [128][64]
    u16* Wt1 = (u16*)alloc(16384 * sizeof(u16));   // [128][128]
    u16* Wt2 = (u16*)alloc(16384 * sizeof(u16));   // [128][128]
    u16* Wtr = (u16*)alloc(8192 * sizeof(u16));    // [64][128]
    u16* xb = (u16*)alloc((size_t)NN * FF * sizeof(u16));     // bf16(x)
    u16* xaggb = (u16*)alloc((size_t)NN * FF * sizeof(u16));  // bf16(Â x)
    u16* bufA = (u16*)alloc((size_t)NN * HH * sizeof(u16));
    u16* bufB = (u16*)alloc((size_t)NN * HH * sizeof(u16));

    hipMemsetAsync(cnt, 0, NN * sizeof(int), stream);

    // fused: edge count + x cast + weight transpose/cast + gemv
    build_k<<<(EE + PREP_ITEMS + 255) / 256, 256, 0, stream>>>(
        ecol, cnt, W0, W1, W2, Wr, Wg, att_src, att_dst, x,
        Wt0, Wt1, Wt2, Wtr, vs, vd, xb);
    chunksum_k<<<NCHUNK, 256, 0, stream>>>(cnt, chunk_sum, dinv1);
    colptr_k<<<NCHUNK, 256, 0, stream>>>(cnt, chunk_sum, col_ptr, cursor);
    fill_k<<<(EE + 255) / 256, 256, 0, stream>>>(erow, ecol, cursor, dinv1, meta1);

    int aggGrid = NN / 8;   // 12500, exact
    const int GG = 512;

    // layer 1: xagg = Â1 x ; y1 = relu(xagg@W0+b0)@W1 fused, + a_s/a_d
    aggx_k<<<aggGrid, 256, 0, stream>>>(xb, col_ptr, meta1, dinv1, xaggb);
    gemm1_k<<<GG, 256, 0, stream>>>(xaggb, Wt0, Wt1, b0, vs, vd, bufB, a_s, a_d);
    // attention
    attn_k<<<(NN + 31) / 32, 256, 0, stream>>>(col_ptr, meta1, a_s, a_d, alpha, dinv2);
    w2_k<<<(EE + 255) / 256, 256, 0, stream>>>(meta1, dinv2, alpha, meta2);
    // layer 2+3 fused: y2 = (relu-agg(y1)+b1)@W2
    agg_gemm_k<HH, false><<<NCHUNKS_M, 256, 0, stream>>>(bufB, col_ptr, meta2, dinv2, b1,
                                                         Wt2, nullptr, bufA);
    // layer 3+readout fused: out = (relu-agg(y2)+b2)@Wr + br
    agg_gemm_k<FF, true><<<NCHUNKS_M, 256, 0, stream>>>(bufA, col_ptr, meta2, dinv2, b2,
                                                        Wtr, br, out);
}

// Round 16
// 274.669 us; speedup vs baseline: 1.2389x; 1.2389x over previous
//
#include <hip/hip_runtime.h>
#include <hip/hip_bf16.h>
#include <hip/hip_fp16.h>
#include <math.h>

#define NN 100000
#define EE 600000
#define FF 64
#define HH 128
#define CHUNK 1024
#define NCHUNK ((NN + CHUNK - 1) / CHUNK)   // 98
#define NCHUNKS_M (NN / 16)                 // 6250 (exact)
#define PREP_ITEMS (NN * FF / 4 + 49280)

typedef unsigned short u16;
typedef unsigned int u32;
typedef __attribute__((ext_vector_type(8))) short bf16x8;
typedef __attribute__((ext_vector_type(4))) float f32x4;

__device__ __forceinline__ u16 f2bf(float f) {
    __hip_bfloat16 h = __float2bfloat16(f);
    return *(u16*)&h;
}
__device__ __forceinline__ float bf2f(u16 u) {
    unsigned int t = ((unsigned int)u) << 16;
    return *(float*)&t;
}
// meta pack: src in bits [31:15], fp16 weight (sign dropped, w>0) in [14:0]
__device__ __forceinline__ u32 enc_meta(int r, float w) {
    u16 hb = __half_as_ushort(__float2half(w));
    return ((u32)r << 15) | (hb & 0x7fffu);
}
__device__ __forceinline__ void dec_meta(u32 u, int& r, float& w) {
    r = (int)(u >> 15);
    w = __half2float(__ushort_as_half((u16)(u & 0x7fffu)));
}

// ---------------- fused: edge count (atomics) + weight/x prep ----------------

__global__ void build_k(const int* __restrict__ col, int* __restrict__ cnt,
                        const float* __restrict__ W0, const float* __restrict__ W1,
                        const float* __restrict__ W2, const float* __restrict__ Wr,
                        const float* __restrict__ Wg, const float* __restrict__ att_src,
                        const float* __restrict__ att_dst, const float* __restrict__ x,
                        u16* __restrict__ Wt0, u16* __restrict__ Wt1,
                        u16* __restrict__ Wt2, u16* __restrict__ Wtr,
                        float* __restrict__ vs, float* __restrict__ vd,
                        u16* __restrict__ xb) {
    int i = blockIdx.x * 256 + threadIdx.x;
    if (i < EE) {
        atomicAdd(&cnt[col[i]], 1);
        return;
    }
    i -= EE;
    if (i < NN * FF / 4) {          // cast x -> bf16
        float4 v = ((const float4*)x)[i];
        ushort4 o;
        o.x = f2bf(v.x); o.y = f2bf(v.y); o.z = f2bf(v.z); o.w = f2bf(v.w);
        ((ushort4*)xb)[i] = o;
        return;
    }
    i -= NN * FF / 4;
    if (i < 8192) {                 // Wt0: [128][64] from W0[64][128]
        int n = i >> 6, k = i & 63;
        Wt0[i] = f2bf(W0[k * 128 + n]);
        return;
    }
    i -= 8192;
    if (i < 16384) {                // Wt1: [128][128]
        int n = i >> 7, k = i & 127;
        Wt1[i] = f2bf(W1[k * 128 + n]);
        return;
    }
    i -= 16384;
    if (i < 16384) {                // Wt2: [128][128]
        int n = i >> 7, k = i & 127;
        Wt2[i] = f2bf(W2[k * 128 + n]);
        return;
    }
    i -= 16384;
    if (i < 8192) {                 // Wtr: [64][128] from Wr[128][64]
        int n = i >> 7, k = i & 127;
        Wtr[i] = f2bf(Wr[k * 64 + n]);
        return;
    }
    i -= 8192;
    if (i < HH) {                   // gemv: vs/vd = Wg @ att_{src,dst}
        float s1 = 0.f, s2 = 0.f;
        for (int j = 0; j < HH; j++) {
            float w = Wg[i * HH + j];
            s1 += w * att_src[j];
            s2 += w * att_dst[j];
        }
        vs[i] = s1;
        vd[i] = s2;
    }
}

// chunk sums + dinv1 fused
__global__ void chunksum_k(const int* __restrict__ cnt, int* __restrict__ chunk_sum,
                           float* __restrict__ dinv1) {
    int b = blockIdx.x, t = threadIdx.x;
    int base = b * CHUNK + t * 4;
    int s = 0;
    #pragma unroll
    for (int i = 0; i < 4; i++) {
        int idx = base + i;
        if (idx < NN) {
            int cv = cnt[idx];
            s += cv;
            dinv1[idx] = rsqrtf((float)cv + 1.0f);
        }
    }
    __shared__ int sm[4];
    for (int d = 32; d > 0; d >>= 1) s += __shfl_down(s, d);
    if ((t & 63) == 0) sm[t >> 6] = s;
    __syncthreads();
    if (t == 0) chunk_sum[b] = sm[0] + sm[1] + sm[2] + sm[3];
}

// col_ptr + cursor; chunk offset computed in-block (98 serial adds)
__global__ void colptr_k(const int* __restrict__ cnt, const int* __restrict__ chunk_sum,
                         int* __restrict__ col_ptr, int* __restrict__ cursor) {
    int b = blockIdx.x, t = threadIdx.x;
    __shared__ int base_off;
    if (t == 0) {
        int run = 0;
        for (int i = 0; i < b; i++) run += chunk_sum[i];
        base_off = run;
        if (b == 0) col_ptr[NN] = EE;
    }
    int base = b * CHUNK + t * 4;
    int c[4]; int tot = 0;
    #pragma unroll
    for (int i = 0; i < 4; i++) { int idx = base + i; c[i] = (idx < NN) ? cnt[idx] : 0; tot += c[i]; }
    __shared__ int s[256];
    s[t] = tot;
    __syncthreads();
    for (int d = 1; d < 256; d <<= 1) {
        int v = (t >= d) ? s[t - d] : 0;
        __syncthreads();
        s[t] += v;
        __syncthreads();
    }
    int excl = s[t] - tot;
    int off = base_off + excl;
    int pre = 0;
    #pragma unroll
    for (int i = 0; i < 4; i++) {
        int idx = base + i;
        if (idx < NN) {
            col_ptr[idx] = off + pre;
            cursor[idx] = off + pre;
        }
        pre += c[i];
    }
}

// fill CSR: single 4B scatter meta1 = enc(src, dinv1[r]*dinv1[c])
__global__ void fill_k(const int* __restrict__ row, const int* __restrict__ col,
                       int* __restrict__ cursor, const float* __restrict__ dinv1,
                       u32* __restrict__ meta1) {
    int e = blockIdx.x * 256 + threadIdx.x;
    if (e < EE) {
        int r = row[e], c = col[e];
        int slot = atomicAdd(&cursor[c], 1);
        meta1[slot] = enc_meta(r, dinv1[r] * dinv1[c]);
    }
}

// ---------------- layer-1 aggregate: 2 nodes/wave, 4 groups x 8 lanes x 2 streams ----------------

__global__ __launch_bounds__(256, 8) void aggx_k(
    const u16* __restrict__ xb, const int* __restrict__ col_ptr, const u32* __restrict__ meta1,
    const float* __restrict__ dinv1, u16* __restrict__ xout) {
    int wid = threadIdx.x >> 6, lane = threadIdx.x & 63;
    int sub = lane >> 5;
    int c = blockIdx.x * 8 + wid * 2 + sub;
    int hl = lane & 31;
    int g = hl >> 3;             // group 0..3
    int ch = (hl & 7) << 3;      // channel base 0,8,...,56
    int beg = col_ptr[c], end = col_ptr[c + 1];
    float acc[8] = {};

    int pA = beg + g, pB = pA + 4;
    int rA = 0, rB = 0; float wA = 0.f, wB = 0.f;
    if (pA < end) dec_meta(meta1[pA], rA, wA);
    if (pB < end) dec_meta(meta1[pB], rB, wB);
    while (pA < end) {
        bool hb = pB < end;
        bf16x8 vA = *(const bf16x8*)&xb[(size_t)rA * FF + ch];
        bf16x8 vB;
        if (hb) vB = *(const bf16x8*)&xb[(size_t)rB * FF + ch];
        int pA2 = pA + 8, pB2 = pB + 8;
        int rA2 = 0, rB2 = 0; float wA2 = 0.f, wB2 = 0.f;
        if (pA2 < end) dec_meta(meta1[pA2], rA2, wA2);
        if (pB2 < end) dec_meta(meta1[pB2], rB2, wB2);
        #pragma unroll
        for (int j = 0; j < 8; j++) acc[j] = fmaf(bf2f((u16)vA[j]), wA, acc[j]);
        if (hb) {
            #pragma unroll
            for (int j = 0; j < 8; j++) acc[j] = fmaf(bf2f((u16)vB[j]), wB, acc[j]);
        }
        pA = pA2; pB = pB2; rA = rA2; rB = rB2; wA = wA2; wB = wB2;
    }
    // combine 4 groups within half-wave (xor 8, 16)
    #pragma unroll
    for (int j = 0; j < 8; j++) {
        acc[j] += __shfl_xor(acc[j], 8);
        acc[j] += __shfl_xor(acc[j], 16);
    }

    if (g == 0) {
        bf16x8 v = *(const bf16x8*)&xb[(size_t)c * FF + ch];
        float dc = dinv1[c];
        float ws = dc * dc;
        bf16x8 o;
        #pragma unroll
        for (int j = 0; j < 8; j++) {
            float t = fmaf(bf2f((u16)v[j]), ws, acc[j]);
            o[j] = (short)f2bf(t);
        }
        *(bf16x8*)&xout[(size_t)c * FF + ch] = o;
    }
}

// ---------------- GEMM1 fused: y1 = (relu(xagg@W0+b0)) @ W1, plus a_s/a_d ----------------

__global__ __launch_bounds__(256) void gemm1_k(const u16* __restrict__ A,
                                               const u16* __restrict__ Wt0,
                                               const u16* __restrict__ Wt1,
                                               const float* __restrict__ bias,
                                               const float* __restrict__ vs, const float* __restrict__ vd,
                                               u16* __restrict__ Y, float* __restrict__ a_s,
                                               float* __restrict__ a_d) {
    constexpr int K = FF, N = HH, KK = K / 32, NT = N / 16, KK2 = HH / 32;
    constexpr int LSTRIDE = 136;
    __shared__ u16 lds[4][16 * LSTRIDE];
    int lane = threadIdx.x & 63, wid = threadIdx.x >> 6;
    int l15 = lane & 15, l4 = lane >> 4;
    int wg = blockIdx.x * 4 + wid;
    int nwaves = gridDim.x * 4;
    u16* myl = &lds[wid][0];

    bf16x8 a_frag[KK][NT];   // W0t fragments resident
    #pragma unroll
    for (int kk = 0; kk < KK; kk++)
        #pragma unroll
        for (int nt = 0; nt < NT; nt++)
            a_frag[kk][nt] = *(const bf16x8*)&Wt0[(size_t)(nt * 16 + l15) * K + kk * 32 + l4 * 8];

    for (int ch = wg; ch < NCHUNKS_M; ch += nwaves) {
        int row = ch * 16 + l15;
        bf16x8 b_frag[KK];
        #pragma unroll
        for (int kk = 0; kk < KK; kk++)
            b_frag[kk] = *(const bf16x8*)&A[(size_t)row * K + kk * 32 + l4 * 8];
        f32x4 acc[NT] = {};
        #pragma unroll
        for (int kk = 0; kk < KK; kk++)
            #pragma unroll
            for (int nt = 0; nt < NT; nt++)
                acc[nt] = __builtin_amdgcn_mfma_f32_16x16x32_bf16(a_frag[kk][nt], b_frag[kk],
                                                                  acc[nt], 0, 0, 0);
        float s1 = 0.f, s2 = 0.f;
        #pragma unroll
        for (int nt = 0; nt < NT; nt++) {
            f32x4 b4 = *(const f32x4*)&bias[nt * 16 + l4 * 4];
            f32x4 v4 = *(const f32x4*)&vs[nt * 16 + l4 * 4];
            f32x4 d4 = *(const f32x4*)&vd[nt * 16 + l4 * 4];
            float o0 = fmaxf(acc[nt][0] + b4[0], 0.f);
            float o1 = fmaxf(acc[nt][1] + b4[1], 0.f);
            float o2 = fmaxf(acc[nt][2] + b4[2], 0.f);
            float o3 = fmaxf(acc[nt][3] + b4[3], 0.f);
            ushort4 o;
            o.x = f2bf(o0); o.y = f2bf(o1); o.z = f2bf(o2); o.w = f2bf(o3);
            *(ushort4*)&myl[l15 * LSTRIDE + nt * 16 + l4 * 4] = o;
            s1 += o0 * v4[0] + o1 * v4[1] + o2 * v4[2] + o3 * v4[3];
            s2 += o0 * d4[0] + o1 * d4[1] + o2 * d4[2] + o3 * d4[3];
        }
        s1 += __shfl_xor(s1, 16); s1 += __shfl_xor(s1, 32);
        s2 += __shfl_xor(s2, 16); s2 += __shfl_xor(s2, 32);
        if (l4 == 0) {
            a_s[row] = s1;
            a_d[row] = s2;
        }
        // second GEMM: read x1 chunk back as B-fragments, multiply by W1t
        bf16x8 b2[KK2];
        #pragma unroll
        for (int kk2 = 0; kk2 < KK2; kk2++)
            b2[kk2] = *(const bf16x8*)&myl[l15 * LSTRIDE + kk2 * 32 + l4 * 8];
        f32x4 acc2[NT] = {};
        #pragma unroll
        for (int kk2 = 0; kk2 < KK2; kk2++)
            #pragma unroll
            for (int nt = 0; nt < NT; nt++) {
                bf16x8 w1f = *(const bf16x8*)&Wt1[(size_t)(nt * 16 + l15) * HH + kk2 * 32 + l4 * 8];
                acc2[nt] = __builtin_amdgcn_mfma_f32_16x16x32_bf16(w1f, b2[kk2], acc2[nt], 0, 0, 0);
            }
        #pragma unroll
        for (int nt = 0; nt < NT; nt++) {
            ushort4 o;
            o.x = f2bf(acc2[nt][0]);
            o.y = f2bf(acc2[nt][1]);
            o.z = f2bf(acc2[nt][2]);
            o.w = f2bf(acc2[nt][3]);
            *(ushort4*)&Y[(size_t)row * HH + nt * 16 + l4 * 4] = o;
        }
    }
}

// ---------------- attention: 8 lanes per node, online softmax ----------------

__global__ __launch_bounds__(256) void attn_k(const int* __restrict__ col_ptr,
                                              const u32* __restrict__ meta1,
                                              const float* __restrict__ a_s,
                                              const float* __restrict__ a_d,
                                              float* __restrict__ alpha,
                                              float* __restrict__ dinv2) {
    int lane = threadIdx.x & 63, wid = threadIdx.x >> 6;
    int grp = lane >> 3, idx = lane & 7;
    int c = blockIdx.x * 32 + wid * 8 + grp;
    if (c >= NN) return;
    int beg = col_ptr[c], end = col_ptr[c + 1];
    float ad = a_d[c];
    float es = a_s[c] + ad;
    es = (es > 0.f) ? es : 0.2f * es;
    float m = (idx == 0) ? es : -1e30f;
    float s = (idx == 0) ? 1.f : 0.f;
    for (int p = beg + idx; p < end; p += 8) {
        float e = a_s[meta1[p] >> 15] + ad;
        e = (e > 0.f) ? e : 0.2f * e;
        alpha[p] = e;
        float mn = fmaxf(m, e);
        s = s * expf(m - mn) + expf(e - mn);
        m = mn;
    }
    #pragma unroll
    for (int d = 1; d < 8; d <<= 1) {
        float mo = __shfl_xor(m, d);
        float so = __shfl_xor(s, d);
        float mn = fmaxf(m, mo);
        s = s * expf(m - mn) + so * expf(mo - mn);
        m = mn;
    }
    float inv = 1.f / s;
    float aself = expf(es - m) * inv;
    float d2 = rsqrtf(2.f - aself);
    if (idx == 0) dinv2[c] = d2;
    float sc = inv * d2;
    for (int p = beg + idx; p < end; p += 8)
        alpha[p] = expf(alpha[p] - m) * sc;
}

// meta2[p] = enc(src, alpha[p] * dinv2[src])
__global__ void w2_k(const u32* __restrict__ meta1, const float* __restrict__ dinv2,
                     const float* __restrict__ alpha, u32* __restrict__ meta2) {
    int p = blockIdx.x * 256 + threadIdx.x;
    if (p < EE) {
        u32 u = meta1[p];
        int r = (int)(u >> 15);
        float w = alpha[p] * dinv2[r];
        u16 hb = __half_as_ushort(__float2half(w));
        meta2[p] = (u & 0xffff8000u) | (hb & 0x7fffu);
    }
}

// ---------------- fused aggregate + GEMM (256 threads, 16 nodes, 6 named streams) ----------------
// Phase 1: 16 lanes/node, six explicitly named edge streams (stride 6) all in
// flight — named scalars so everything stays in registers (r15's arrays spilled).
// Phase 2: wave wid computes n-tiles [wid*NT_W,(wid+1)*NT_W) of 16x128 @ 128xNOUT.

template <int NOUT, bool OUTF32>
__global__ __launch_bounds__(256, 8) void agg_gemm_k(
    const u16* __restrict__ xw, const int* __restrict__ col_ptr, const u32* __restrict__ meta,
    const float* __restrict__ dinv2, const float* __restrict__ bias_in,
    const u16* __restrict__ Wt, const float* __restrict__ bias_out, void* __restrict__ Y_) {
    constexpr int KK2 = HH / 32;        // 4
    constexpr int NT = NOUT / 16;       // 8 or 4
    constexpr int NT_W = NT / 4;        // 2 or 1
    constexpr int LSTRIDE = 136;
    __shared__ u16 lds[16 * LSTRIDE];
    int tid = threadIdx.x;
    int lane = tid & 63, wid = tid >> 6;
    int node = tid >> 4;                // 0..15
    int ch = (tid & 15) << 3;           // channel base 0..120
    int cbase = blockIdx.x * 16;
    int c = cbase + node;
    int beg = col_ptr[c], end = col_ptr[c + 1];
    float acc[8] = {};

    // phase 1: six named streams, stride 6
    int pA = beg,     pB = beg + 1, pC = beg + 2;
    int pD = beg + 3, pE = beg + 4, pF = beg + 5;
    int rA = 0, rB = 0, rC = 0, rD = 0, rE = 0, rF = 0;
    float wA = 0.f, wB = 0.f, wC = 0.f, wD = 0.f, wE = 0.f, wF = 0.f;
    if (pA < end) dec_meta(meta[pA], rA, wA);
    if (pB < end) dec_meta(meta[pB], rB, wB);
    if (pC < end) dec_meta(meta[pC], rC, wC);
    if (pD < end) dec_meta(meta[pD], rD, wD);
    if (pE < end) dec_meta(meta[pE], rE, wE);
    if (pF < end) dec_meta(meta[pF], rF, wF);
    while (pA < end) {
        bool hb = pB < end, hc = pC < end, hd = pD < end, he = pE < end, hf = pF < end;
        bf16x8 vA = *(const bf16x8*)&xw[(size_t)rA * HH + ch];
        bf16x8 vB, vC, vD, vE, vF;
        if (hb) vB = *(const bf16x8*)&xw[(size_t)rB * HH + ch];
        if (hc) vC = *(const bf16x8*)&xw[(size_t)rC * HH + ch];
        if (hd) vD = *(const bf16x8*)&xw[(size_t)rD * HH + ch];
        if (he) vE = *(const bf16x8*)&xw[(size_t)rE * HH + ch];
        if (hf) vF = *(const bf16x8*)&xw[(size_t)rF * HH + ch];
        pA += 6; pB += 6; pC += 6; pD += 6; pE += 6; pF += 6;
        int rA2 = 0, rB2 = 0, rC2 = 0, rD2 = 0, rE2 = 0, rF2 = 0;
        float wA2 = 0.f, wB2 = 0.f, wC2 = 0.f, wD2 = 0.f, wE2 = 0.f, wF2 = 0.f;
        if (pA < end) dec_meta(meta[pA], rA2, wA2);
        if (pB < end) dec_meta(meta[pB], rB2, wB2);
        if (pC < end) dec_meta(meta[pC], rC2, wC2);
        if (pD < end) dec_meta(meta[pD], rD2, wD2);
        if (pE < end) dec_meta(meta[pE], rE2, wE2);
        if (pF < end) dec_meta(meta[pF], rF2, wF2);
        #pragma unroll
        for (int j = 0; j < 8; j++) acc[j] = fmaf(bf2f((u16)vA[j]), wA, acc[j]);
        if (hb) {
            #pragma unroll
            for (int j = 0; j < 8; j++) acc[j] = fmaf(bf2f((u16)vB[j]), wB, acc[j]);
        }
        if (hc) {
            #pragma unroll
            for (int j = 0; j < 8; j++) acc[j] = fmaf(bf2f((u16)vC[j]), wC, acc[j]);
        }
        if (hd) {
            #pragma unroll
            for (int j = 0; j < 8; j++) acc[j] = fmaf(bf2f((u16)vD[j]), wD, acc[j]);
        }
        if (he) {
            #pragma unroll
            for (int j = 0; j < 8; j++) acc[j] = fmaf(bf2f((u16)vE[j]), wE, acc[j]);
        }
        if (hf) {
            #pragma unroll
            for (int j = 0; j < 8; j++) acc[j] = fmaf(bf2f((u16)vF[j]), wF, acc[j]);
        }
        rA = rA2; rB = rB2; rC = rC2; rD = rD2; rE = rE2; rF = rF2;
        wA = wA2; wB = wB2; wC = wC2; wD = wD2; wE = wE2; wF = wF2;
    }
    {   // self loop + bias_in + relu -> LDS row (bf16)
        bf16x8 v = *(const bf16x8*)&xw[(size_t)c * HH + ch];
        float dc = dinv2[c];
        float ws = dc * dc;
        f32x4 b4a = *(const f32x4*)&bias_in[ch];
        f32x4 b4b = *(const f32x4*)&bias_in[ch + 4];
        bf16x8 o;
        #pragma unroll
        for (int j = 0; j < 8; j++) {
            float bj = (j < 4) ? b4a[j] : b4b[j - 4];
            float t = fmaxf(fmaf(bf2f((u16)v[j]), ws, acc[j]) + bj, 0.f);
            o[j] = (short)f2bf(t);
        }
        *(bf16x8*)&lds[node * LSTRIDE + ch] = o;
    }
    __syncthreads();

    // phase 2: wave wid handles n-tiles [wid*NT_W, (wid+1)*NT_W)
    int l15 = lane & 15, l4 = lane >> 4;
    bf16x8 b2[KK2];
    #pragma unroll
    for (int kk2 = 0; kk2 < KK2; kk2++)
        b2[kk2] = *(const bf16x8*)&lds[l15 * LSTRIDE + kk2 * 32 + l4 * 8];
    int row = cbase + l15;
    #pragma unroll
    for (int ntw = 0; ntw < NT_W; ntw++) {
        int nt = wid * NT_W + ntw;
        f32x4 acc2 = {};
        #pragma unroll
        for (int kk2 = 0; kk2 < KK2; kk2++) {
            bf16x8 wf = *(const bf16x8*)&Wt[(size_t)(nt * 16 + l15) * HH + kk2 * 32 + l4 * 8];
            acc2 = __builtin_amdgcn_mfma_f32_16x16x32_bf16(wf, b2[kk2], acc2, 0, 0, 0);
        }
        int col = nt * 16 + l4 * 4;
        if (OUTF32) {
            float4 o;
            f32x4 bo = *(const f32x4*)&bias_out[col];
            o.x = acc2[0] + bo[0];
            o.y = acc2[1] + bo[1];
            o.z = acc2[2] + bo[2];
            o.w = acc2[3] + bo[3];
            *(float4*)&((float*)Y_)[(size_t)row * NOUT + col] = o;
        } else {
            ushort4 o;
            o.x = f2bf(acc2[0]);
            o.y = f2bf(acc2[1]);
            o.z = f2bf(acc2[2]);
            o.w = f2bf(acc2[3]);
            *(ushort4*)&((u16*)Y_)[(size_t)row * NOUT + col] = o;
        }
    }
}

// ---------------- launch ----------------

extern "C" void kernel_launch(void* const* d_in, const int* in_sizes, int n_in,
                              void* d_out, int out_size, void* d_ws, size_t ws_size,
                              hipStream_t stream) {
    const float* x = (const float*)d_in[0];
    const int* eidx = (const int*)d_in[1];     // [2][E]: row, col
    const float* W0 = (const float*)d_in[3];
    const float* b0 = (const float*)d_in[4];
    const float* Wg = (const float*)d_in[5];
    const float* att_src = (const float*)d_in[6];
    const float* att_dst = (const float*)d_in[7];
    const float* W1 = (const float*)d_in[8];
    const float* b1 = (const float*)d_in[9];
    const float* W2 = (const float*)d_in[10];
    const float* b2 = (const float*)d_in[11];
    const float* Wr = (const float*)d_in[12];
    const float* br = (const float*)d_in[13];
    float* out = (float*)d_out;

    const int* erow = eidx;
    const int* ecol = eidx + EE;

    char* p = (char*)d_ws;
    auto alloc = [&](size_t bytes) {
        void* r = (void*)p;
        p += (bytes + 255) & ~(size_t)255;
        return r;
    };
    int* col_ptr = (int*)alloc((NN + 1) * sizeof(int));
    u32* meta1 = (u32*)alloc(EE * sizeof(u32));
    u32* meta2 = (u32*)alloc(EE * sizeof(u32));
    int* cnt = (int*)alloc(NN * sizeof(int));
    int* cursor = (int*)alloc(NN * sizeof(int));
    int* chunk_sum = (int*)alloc(128 * sizeof(int));
    float* alpha = (float*)alloc(EE * sizeof(float));
    float* dinv1 = (float*)alloc(NN * sizeof(float));
    float* dinv2 = (float*)alloc(NN * sizeof(float));
    float* a_s = (float*)alloc(NN * sizeof(float));
    float* a_d = (float*)alloc(NN * sizeof(float));
    float* vs = (float*)alloc(HH * sizeof(float));
    float* vd = (float*)alloc(HH * sizeof(float));
    u16* Wt0 = (u16*)alloc(8192 * sizeof(u16));    // [128][64]
    u16* Wt1 = (u16*)alloc(16384 * sizeof(u16));   // [128][128]
    u16* Wt2 = (u16*)alloc(16384 * sizeof(u16));   // [128][128]
    u16* Wtr = (u16*)alloc(8192 * sizeof(u16));    // [64][128]
    u16* xb = (u16*)alloc((size_t)NN * FF * sizeof(u16));     // bf16(x)
    u16* xaggb = (u16*)alloc((size_t)NN * FF * sizeof(u16));  // bf16(Â x)
    u16* bufA = (u16*)alloc((size_t)NN * HH * sizeof(u16));
    u16* bufB = (u16*)alloc((size_t)NN * HH * sizeof(u16));

    hipMemsetAsync(cnt, 0, NN * sizeof(int), stream);

    // fused: edge count + x cast + weight transpose/cast + gemv
    build_k<<<(EE + PREP_ITEMS + 255) / 256, 256, 0, stream>>>(
        ecol, cnt, W0, W1, W2, Wr, Wg, att_src, att_dst, x,
        Wt0, Wt1, Wt2, Wtr, vs, vd, xb);
    chunksum_k<<<NCHUNK, 256, 0, stream>>>(cnt, chunk_sum, dinv1);
    colptr_k<<<NCHUNK, 256, 0, stream>>>(cnt, chunk_sum, col_ptr, cursor);
    fill_k<<<(EE + 255) / 256, 256, 0, stream>>>(erow, ecol, cursor, dinv1, meta1);

    int aggGrid = NN / 8;   // 12500, exact
    const int GG = 512;

    // layer 1: xagg = Â1 x ; y1 = relu(xagg@W0+b0)@W1 fused, + a_s/a_d
    aggx_k<<<aggGrid, 256, 0, stream>>>(xb, col_ptr, meta1, dinv1, xaggb);
    gemm1_k<<<GG, 256, 0, stream>>>(xaggb, Wt0, Wt1, b0, vs, vd, bufB, a_s, a_d);
    // attention
    attn_k<<<(NN + 31) / 32, 256, 0, stream>>>(col_ptr, meta1, a_s, a_d, alpha, dinv2);
    w2_k<<<(EE + 255) / 256, 256, 0, stream>>>(meta1, dinv2, alpha, meta2);
    // layer 2+3 fused: y2 = (relu-agg(y1)+b1)@W2
    agg_gemm_k<HH, false><<<NCHUNKS_M, 256, 0, stream>>>(bufB, col_ptr, meta2, dinv2, b1,
                                                         Wt2, nullptr, bufA);
    // layer 3+readout fused: out = (relu-agg(y2)+b2)@Wr + br
    agg_gemm_k<FF, true><<<NCHUNKS_M, 256, 0, stream>>>(bufA, col_ptr, meta2, dinv2, b2,
                                                        Wtr, br, out);
}

// Round 17
// 261.994 us; speedup vs baseline: 1.2988x; 1.0484x over previous
//
#include <hip/hip_runtime.h>
#include <hip/hip_bf16.h>
#include <hip/hip_fp16.h>
#include <math.h>

#define NN 100000
#define EE 600000
#define FF 64
#define HH 128
#define CHUNK 1024
#define NCHUNK ((NN + CHUNK - 1) / CHUNK)   // 98
#define NCHUNKS_M (NN / 16)                 // 6250 (exact)
#define PREP_ITEMS (NN * FF / 4 + 49280)

typedef unsigned short u16;
typedef unsigned int u32;
typedef __attribute__((ext_vector_type(8))) short bf16x8;
typedef __attribute__((ext_vector_type(4))) float f32x4;

__device__ __forceinline__ u16 f2bf(float f) {
    __hip_bfloat16 h = __float2bfloat16(f);
    return *(u16*)&h;
}
__device__ __forceinline__ float bf2f(u16 u) {
    unsigned int t = ((unsigned int)u) << 16;
    return *(float*)&t;
}
// meta pack: src in bits [31:15], fp16 weight (sign dropped, w>0) in [14:0]
__device__ __forceinline__ u32 enc_meta(int r, float w) {
    u16 hb = __half_as_ushort(__float2half(w));
    return ((u32)r << 15) | (hb & 0x7fffu);
}
__device__ __forceinline__ void dec_meta(u32 u, int& r, float& w) {
    r = (int)(u >> 15);
    w = __half2float(__ushort_as_half((u16)(u & 0x7fffu)));
}

// ---------------- fused: edge count (atomics) + weight/x prep ----------------

__global__ void build_k(const int* __restrict__ col, int* __restrict__ cnt,
                        const float* __restrict__ W0, const float* __restrict__ W1,
                        const float* __restrict__ W2, const float* __restrict__ Wr,
                        const float* __restrict__ Wg, const float* __restrict__ att_src,
                        const float* __restrict__ att_dst, const float* __restrict__ x,
                        u16* __restrict__ Wt0, u16* __restrict__ Wt1,
                        u16* __restrict__ Wt2, u16* __restrict__ Wtr,
                        float* __restrict__ vs, float* __restrict__ vd,
                        u16* __restrict__ xb) {
    int i = blockIdx.x * 256 + threadIdx.x;
    if (i < EE) {
        atomicAdd(&cnt[col[i]], 1);
        return;
    }
    i -= EE;
    if (i < NN * FF / 4) {          // cast x -> bf16
        float4 v = ((const float4*)x)[i];
        ushort4 o;
        o.x = f2bf(v.x); o.y = f2bf(v.y); o.z = f2bf(v.z); o.w = f2bf(v.w);
        ((ushort4*)xb)[i] = o;
        return;
    }
    i -= NN * FF / 4;
    if (i < 8192) {                 // Wt0: [128][64] from W0[64][128]
        int n = i >> 6, k = i & 63;
        Wt0[i] = f2bf(W0[k * 128 + n]);
        return;
    }
    i -= 8192;
    if (i < 16384) {                // Wt1: [128][128]
        int n = i >> 7, k = i & 127;
        Wt1[i] = f2bf(W1[k * 128 + n]);
        return;
    }
    i -= 16384;
    if (i < 16384) {                // Wt2: [128][128]
        int n = i >> 7, k = i & 127;
        Wt2[i] = f2bf(W2[k * 128 + n]);
        return;
    }
    i -= 16384;
    if (i < 8192) {                 // Wtr: [64][128] from Wr[128][64]
        int n = i >> 7, k = i & 127;
        Wtr[i] = f2bf(Wr[k * 64 + n]);
        return;
    }
    i -= 8192;
    if (i < HH) {                   // gemv: vs/vd = Wg @ att_{src,dst}
        float s1 = 0.f, s2 = 0.f;
        for (int j = 0; j < HH; j++) {
            float w = Wg[i * HH + j];
            s1 += w * att_src[j];
            s2 += w * att_dst[j];
        }
        vs[i] = s1;
        vd[i] = s2;
    }
}

// chunk sums + dinv1 fused
__global__ void chunksum_k(const int* __restrict__ cnt, int* __restrict__ chunk_sum,
                           float* __restrict__ dinv1) {
    int b = blockIdx.x, t = threadIdx.x;
    int base = b * CHUNK + t * 4;
    int s = 0;
    #pragma unroll
    for (int i = 0; i < 4; i++) {
        int idx = base + i;
        if (idx < NN) {
            int cv = cnt[idx];
            s += cv;
            dinv1[idx] = rsqrtf((float)cv + 1.0f);
        }
    }
    __shared__ int sm[4];
    for (int d = 32; d > 0; d >>= 1) s += __shfl_down(s, d);
    if ((t & 63) == 0) sm[t >> 6] = s;
    __syncthreads();
    if (t == 0) chunk_sum[b] = sm[0] + sm[1] + sm[2] + sm[3];
}

// col_ptr + cursor; chunk offset computed in-block (98 serial adds)
__global__ void colptr_k(const int* __restrict__ cnt, const int* __restrict__ chunk_sum,
                         int* __restrict__ col_ptr, int* __restrict__ cursor) {
    int b = blockIdx.x, t = threadIdx.x;
    __shared__ int base_off;
    if (t == 0) {
        int run = 0;
        for (int i = 0; i < b; i++) run += chunk_sum[i];
        base_off = run;
        if (b == 0) col_ptr[NN] = EE;
    }
    int base = b * CHUNK + t * 4;
    int c[4]; int tot = 0;
    #pragma unroll
    for (int i = 0; i < 4; i++) { int idx = base + i; c[i] = (idx < NN) ? cnt[idx] : 0; tot += c[i]; }
    __shared__ int s[256];
    s[t] = tot;
    __syncthreads();
    for (int d = 1; d < 256; d <<= 1) {
        int v = (t >= d) ? s[t - d] : 0;
        __syncthreads();
        s[t] += v;
        __syncthreads();
    }
    int excl = s[t] - tot;
    int off = base_off + excl;
    int pre = 0;
    #pragma unroll
    for (int i = 0; i < 4; i++) {
        int idx = base + i;
        if (idx < NN) {
            col_ptr[idx] = off + pre;
            cursor[idx] = off + pre;
        }
        pre += c[i];
    }
}

// fill CSR: single 4B scatter meta1 = enc(src, dinv1[r]*dinv1[c])
__global__ void fill_k(const int* __restrict__ row, const int* __restrict__ col,
                       int* __restrict__ cursor, const float* __restrict__ dinv1,
                       u32* __restrict__ meta1) {
    int e = blockIdx.x * 256 + threadIdx.x;
    if (e < EE) {
        int r = row[e], c = col[e];
        int slot = atomicAdd(&cursor[c], 1);
        meta1[slot] = enc_meta(r, dinv1[r] * dinv1[c]);
    }
}

// ---------------- layer-1 aggregate: 2 nodes/wave, 4 groups x 8 lanes x 2 streams ----------------

__global__ __launch_bounds__(256, 8) void aggx_k(
    const u16* __restrict__ xb, const int* __restrict__ col_ptr, const u32* __restrict__ meta1,
    const float* __restrict__ dinv1, u16* __restrict__ xout) {
    int wid = threadIdx.x >> 6, lane = threadIdx.x & 63;
    int sub = lane >> 5;
    int c = blockIdx.x * 8 + wid * 2 + sub;
    int hl = lane & 31;
    int g = hl >> 3;             // group 0..3
    int ch = (hl & 7) << 3;      // channel base 0,8,...,56
    int beg = col_ptr[c], end = col_ptr[c + 1];
    float acc[8] = {};

    int pA = beg + g, pB = pA + 4;
    int rA = 0, rB = 0; float wA = 0.f, wB = 0.f;
    if (pA < end) dec_meta(meta1[pA], rA, wA);
    if (pB < end) dec_meta(meta1[pB], rB, wB);
    while (pA < end) {
        bool hb = pB < end;
        bf16x8 vA = *(const bf16x8*)&xb[(size_t)rA * FF + ch];
        bf16x8 vB;
        if (hb) vB = *(const bf16x8*)&xb[(size_t)rB * FF + ch];
        int pA2 = pA + 8, pB2 = pB + 8;
        int rA2 = 0, rB2 = 0; float wA2 = 0.f, wB2 = 0.f;
        if (pA2 < end) dec_meta(meta1[pA2], rA2, wA2);
        if (pB2 < end) dec_meta(meta1[pB2], rB2, wB2);
        #pragma unroll
        for (int j = 0; j < 8; j++) acc[j] = fmaf(bf2f((u16)vA[j]), wA, acc[j]);
        if (hb) {
            #pragma unroll
            for (int j = 0; j < 8; j++) acc[j] = fmaf(bf2f((u16)vB[j]), wB, acc[j]);
        }
        pA = pA2; pB = pB2; rA = rA2; rB = rB2; wA = wA2; wB = wB2;
    }
    // combine 4 groups within half-wave (xor 8, 16)
    #pragma unroll
    for (int j = 0; j < 8; j++) {
        acc[j] += __shfl_xor(acc[j], 8);
        acc[j] += __shfl_xor(acc[j], 16);
    }

    if (g == 0) {
        bf16x8 v = *(const bf16x8*)&xb[(size_t)c * FF + ch];
        float dc = dinv1[c];
        float ws = dc * dc;
        bf16x8 o;
        #pragma unroll
        for (int j = 0; j < 8; j++) {
            float t = fmaf(bf2f((u16)v[j]), ws, acc[j]);
            o[j] = (short)f2bf(t);
        }
        *(bf16x8*)&xout[(size_t)c * FF + ch] = o;
    }
}

// ---------------- GEMM1 fused: y1 = (relu(xagg@W0+b0)) @ W1, plus a_s/a_d ----------------

__global__ __launch_bounds__(256) void gemm1_k(const u16* __restrict__ A,
                                               const u16* __restrict__ Wt0,
                                               const u16* __restrict__ Wt1,
                                               const float* __restrict__ bias,
                                               const float* __restrict__ vs, const float* __restrict__ vd,
                                               u16* __restrict__ Y, float* __restrict__ a_s,
                                               float* __restrict__ a_d) {
    constexpr int K = FF, N = HH, KK = K / 32, NT = N / 16, KK2 = HH / 32;
    constexpr int LSTRIDE = 136;
    __shared__ u16 lds[4][16 * LSTRIDE];
    int lane = threadIdx.x & 63, wid = threadIdx.x >> 6;
    int l15 = lane & 15, l4 = lane >> 4;
    int wg = blockIdx.x * 4 + wid;
    int nwaves = gridDim.x * 4;
    u16* myl = &lds[wid][0];

    bf16x8 a_frag[KK][NT];   // W0t fragments resident
    #pragma unroll
    for (int kk = 0; kk < KK; kk++)
        #pragma unroll
        for (int nt = 0; nt < NT; nt++)
            a_frag[kk][nt] = *(const bf16x8*)&Wt0[(size_t)(nt * 16 + l15) * K + kk * 32 + l4 * 8];

    for (int ch = wg; ch < NCHUNKS_M; ch += nwaves) {
        int row = ch * 16 + l15;
        bf16x8 b_frag[KK];
        #pragma unroll
        for (int kk = 0; kk < KK; kk++)
            b_frag[kk] = *(const bf16x8*)&A[(size_t)row * K + kk * 32 + l4 * 8];
        f32x4 acc[NT] = {};
        #pragma unroll
        for (int kk = 0; kk < KK; kk++)
            #pragma unroll
            for (int nt = 0; nt < NT; nt++)
                acc[nt] = __builtin_amdgcn_mfma_f32_16x16x32_bf16(a_frag[kk][nt], b_frag[kk],
                                                                  acc[nt], 0, 0, 0);
        float s1 = 0.f, s2 = 0.f;
        #pragma unroll
        for (int nt = 0; nt < NT; nt++) {
            f32x4 b4 = *(const f32x4*)&bias[nt * 16 + l4 * 4];
            f32x4 v4 = *(const f32x4*)&vs[nt * 16 + l4 * 4];
            f32x4 d4 = *(const f32x4*)&vd[nt * 16 + l4 * 4];
            float o0 = fmaxf(acc[nt][0] + b4[0], 0.f);
            float o1 = fmaxf(acc[nt][1] + b4[1], 0.f);
            float o2 = fmaxf(acc[nt][2] + b4[2], 0.f);
            float o3 = fmaxf(acc[nt][3] + b4[3], 0.f);
            ushort4 o;
            o.x = f2bf(o0); o.y = f2bf(o1); o.z = f2bf(o2); o.w = f2bf(o3);
            *(ushort4*)&myl[l15 * LSTRIDE + nt * 16 + l4 * 4] = o;
            s1 += o0 * v4[0] + o1 * v4[1] + o2 * v4[2] + o3 * v4[3];
            s2 += o0 * d4[0] + o1 * d4[1] + o2 * d4[2] + o3 * d4[3];
        }
        s1 += __shfl_xor(s1, 16); s1 += __shfl_xor(s1, 32);
        s2 += __shfl_xor(s2, 16); s2 += __shfl_xor(s2, 32);
        if (l4 == 0) {
            a_s[row] = s1;
            a_d[row] = s2;
        }
        // second GEMM: read x1 chunk back as B-fragments, multiply by W1t
        bf16x8 b2[KK2];
        #pragma unroll
        for (int kk2 = 0; kk2 < KK2; kk2++)
            b2[kk2] = *(const bf16x8*)&myl[l15 * LSTRIDE + kk2 * 32 + l4 * 8];
        f32x4 acc2[NT] = {};
        #pragma unroll
        for (int kk2 = 0; kk2 < KK2; kk2++)
            #pragma unroll
            for (int nt = 0; nt < NT; nt++) {
                bf16x8 w1f = *(const bf16x8*)&Wt1[(size_t)(nt * 16 + l15) * HH + kk2 * 32 + l4 * 8];
                acc2[nt] = __builtin_amdgcn_mfma_f32_16x16x32_bf16(w1f, b2[kk2], acc2[nt], 0, 0, 0);
            }
        #pragma unroll
        for (int nt = 0; nt < NT; nt++) {
            ushort4 o;
            o.x = f2bf(acc2[nt][0]);
            o.y = f2bf(acc2[nt][1]);
            o.z = f2bf(acc2[nt][2]);
            o.w = f2bf(acc2[nt][3]);
            *(ushort4*)&Y[(size_t)row * HH + nt * 16 + l4 * 4] = o;
        }
    }
}

// ---------------- attention: 8 lanes per node, online softmax ----------------

__global__ __launch_bounds__(256) void attn_k(const int* __restrict__ col_ptr,
                                              const u32* __restrict__ meta1,
                                              const float* __restrict__ a_s,
                                              const float* __restrict__ a_d,
                                              float* __restrict__ alpha,
                                              float* __restrict__ dinv2) {
    int lane = threadIdx.x & 63, wid = threadIdx.x >> 6;
    int grp = lane >> 3, idx = lane & 7;
    int c = blockIdx.x * 32 + wid * 8 + grp;
    if (c >= NN) return;
    int beg = col_ptr[c], end = col_ptr[c + 1];
    float ad = a_d[c];
    float es = a_s[c] + ad;
    es = (es > 0.f) ? es : 0.2f * es;
    float m = (idx == 0) ? es : -1e30f;
    float s = (idx == 0) ? 1.f : 0.f;
    for (int p = beg + idx; p < end; p += 8) {
        float e = a_s[meta1[p] >> 15] + ad;
        e = (e > 0.f) ? e : 0.2f * e;
        alpha[p] = e;
        float mn = fmaxf(m, e);
        s = s * expf(m - mn) + expf(e - mn);
        m = mn;
    }
    #pragma unroll
    for (int d = 1; d < 8; d <<= 1) {
        float mo = __shfl_xor(m, d);
        float so = __shfl_xor(s, d);
        float mn = fmaxf(m, mo);
        s = s * expf(m - mn) + so * expf(mo - mn);
        m = mn;
    }
    float inv = 1.f / s;
    float aself = expf(es - m) * inv;
    float d2 = rsqrtf(2.f - aself);
    if (idx == 0) dinv2[c] = d2;
    float sc = inv * d2;
    for (int p = beg + idx; p < end; p += 8)
        alpha[p] = expf(alpha[p] - m) * sc;
}

// meta2[p] = enc(src, alpha[p] * dinv2[src])
__global__ void w2_k(const u32* __restrict__ meta1, const float* __restrict__ dinv2,
                     const float* __restrict__ alpha, u32* __restrict__ meta2) {
    int p = blockIdx.x * 256 + threadIdx.x;
    if (p < EE) {
        u32 u = meta1[p];
        int r = (int)(u >> 15);
        float w = alpha[p] * dinv2[r];
        u16 hb = __half_as_ushort(__float2half(w));
        meta2[p] = (u & 0xffff8000u) | (hb & 0x7fffu);
    }
}

// ---------------- fused aggregate + GEMM (256 threads, 8 nodes) ----------------
// Phase 1: r12 agg2 geometry — 2 nodes/wave, 2 groups x 16 lanes x 3 named
// streams (6 edges in flight/node, stride 6); rows land in an 8x136 LDS tile.
// Phase 2: MFMA with 8 valid B-rows (lanes 8-15 duplicate row l15&7, no store).

template <int NOUT, bool OUTF32>
__global__ __launch_bounds__(256, 8) void agg_gemm_k(
    const u16* __restrict__ xw, const int* __restrict__ col_ptr, const u32* __restrict__ meta,
    const float* __restrict__ dinv2, const float* __restrict__ bias_in,
    const u16* __restrict__ Wt, const float* __restrict__ bias_out, void* __restrict__ Y_) {
    constexpr int KK2 = HH / 32;        // 4
    constexpr int NT = NOUT / 16;       // 8 or 4
    constexpr int NT_W = NT / 4;        // 2 or 1
    constexpr int LSTRIDE = 136;
    __shared__ u16 lds[8 * LSTRIDE];
    int tid = threadIdx.x;
    int lane = tid & 63, wid = tid >> 6;
    int sub = lane >> 5;
    int node = wid * 2 + sub;           // 0..7
    int hl = lane & 31;
    int g = hl >> 4;                    // group 0..1
    int ch = (hl & 15) << 3;            // channel base 0..120
    int cbase = blockIdx.x * 8;
    int c = cbase + node;
    int beg = col_ptr[c], end = col_ptr[c + 1];
    float acc[8] = {};

    // phase 1: 2 groups x 3 named streams (stride 6) — r12's proven no-spill loop
    int pA = beg + g, pB = pA + 2, pC = pA + 4;
    int rA = 0, rB = 0, rC = 0; float wA = 0.f, wB = 0.f, wC = 0.f;
    if (pA < end) dec_meta(meta[pA], rA, wA);
    if (pB < end) dec_meta(meta[pB], rB, wB);
    if (pC < end) dec_meta(meta[pC], rC, wC);
    while (pA < end) {
        bool hb = pB < end, hc = pC < end;
        bf16x8 vA = *(const bf16x8*)&xw[(size_t)rA * HH + ch];
        bf16x8 vB, vC;
        if (hb) vB = *(const bf16x8*)&xw[(size_t)rB * HH + ch];
        if (hc) vC = *(const bf16x8*)&xw[(size_t)rC * HH + ch];
        int pA2 = pA + 6, pB2 = pB + 6, pC2 = pC + 6;
        int rA2 = 0, rB2 = 0, rC2 = 0; float wA2 = 0.f, wB2 = 0.f, wC2 = 0.f;
        if (pA2 < end) dec_meta(meta[pA2], rA2, wA2);
        if (pB2 < end) dec_meta(meta[pB2], rB2, wB2);
        if (pC2 < end) dec_meta(meta[pC2], rC2, wC2);
        #pragma unroll
        for (int j = 0; j < 8; j++) acc[j] = fmaf(bf2f((u16)vA[j]), wA, acc[j]);
        if (hb) {
            #pragma unroll
            for (int j = 0; j < 8; j++) acc[j] = fmaf(bf2f((u16)vB[j]), wB, acc[j]);
        }
        if (hc) {
            #pragma unroll
            for (int j = 0; j < 8; j++) acc[j] = fmaf(bf2f((u16)vC[j]), wC, acc[j]);
        }
        pA = pA2; pB = pB2; pC = pC2;
        rA = rA2; rB = rB2; rC = rC2;
        wA = wA2; wB = wB2; wC = wC2;
    }
    // combine 2 groups within half-wave (xor 16)
    #pragma unroll
    for (int j = 0; j < 8; j++) acc[j] += __shfl_xor(acc[j], 16);

    if (g == 0) {   // self loop + bias_in + relu -> LDS row (bf16)
        bf16x8 v = *(const bf16x8*)&xw[(size_t)c * HH + ch];
        float dc = dinv2[c];
        float ws = dc * dc;
        f32x4 b4a = *(const f32x4*)&bias_in[ch];
        f32x4 b4b = *(const f32x4*)&bias_in[ch + 4];
        bf16x8 o;
        #pragma unroll
        for (int j = 0; j < 8; j++) {
            float bj = (j < 4) ? b4a[j] : b4b[j - 4];
            float t = fmaxf(fmaf(bf2f((u16)v[j]), ws, acc[j]) + bj, 0.f);
            o[j] = (short)f2bf(t);
        }
        *(bf16x8*)&lds[node * LSTRIDE + ch] = o;
    }
    __syncthreads();

    // phase 2: wave wid handles n-tiles [wid*NT_W, (wid+1)*NT_W); rows 8-15 dup.
    int l15 = lane & 15, l4 = lane >> 4;
    int lrow = l15 & 7;
    bf16x8 b2[KK2];
    #pragma unroll
    for (int kk2 = 0; kk2 < KK2; kk2++)
        b2[kk2] = *(const bf16x8*)&lds[lrow * LSTRIDE + kk2 * 32 + l4 * 8];
    int row = cbase + l15;
    #pragma unroll
    for (int ntw = 0; ntw < NT_W; ntw++) {
        int nt = wid * NT_W + ntw;
        f32x4 acc2 = {};
        #pragma unroll
        for (int kk2 = 0; kk2 < KK2; kk2++) {
            bf16x8 wf = *(const bf16x8*)&Wt[(size_t)(nt * 16 + l15) * HH + kk2 * 32 + l4 * 8];
            acc2 = __builtin_amdgcn_mfma_f32_16x16x32_bf16(wf, b2[kk2], acc2, 0, 0, 0);
        }
        if (l15 < 8) {
            int col = nt * 16 + l4 * 4;
            if (OUTF32) {
                float4 o;
                f32x4 bo = *(const f32x4*)&bias_out[col];
                o.x = acc2[0] + bo[0];
                o.y = acc2[1] + bo[1];
                o.z = acc2[2] + bo[2];
                o.w = acc2[3] + bo[3];
                *(float4*)&((float*)Y_)[(size_t)row * NOUT + col] = o;
            } else {
                ushort4 o;
                o.x = f2bf(acc2[0]);
                o.y = f2bf(acc2[1]);
                o.z = f2bf(acc2[2]);
                o.w = f2bf(acc2[3]);
                *(ushort4*)&((u16*)Y_)[(size_t)row * NOUT + col] = o;
            }
        }
    }
}

// ---------------- launch ----------------

extern "C" void kernel_launch(void* const* d_in, const int* in_sizes, int n_in,
                              void* d_out, int out_size, void* d_ws, size_t ws_size,
                              hipStream_t stream) {
    const float* x = (const float*)d_in[0];
    const int* eidx = (const int*)d_in[1];     // [2][E]: row, col
    const float* W0 = (const float*)d_in[3];
    const float* b0 = (const float*)d_in[4];
    const float* Wg = (const float*)d_in[5];
    const float* att_src = (const float*)d_in[6];
    const float* att_dst = (const float*)d_in[7];
    const float* W1 = (const float*)d_in[8];
    const float* b1 = (const float*)d_in[9];
    const float* W2 = (const float*)d_in[10];
    const float* b2 = (const float*)d_in[11];
    const float* Wr = (const float*)d_in[12];
    const float* br = (const float*)d_in[13];
    float* out = (float*)d_out;

    const int* erow = eidx;
    const int* ecol = eidx + EE;

    char* p = (char*)d_ws;
    auto alloc = [&](size_t bytes) {
        void* r = (void*)p;
        p += (bytes + 255) & ~(size_t)255;
        return r;
    };
    int* col_ptr = (int*)alloc((NN + 1) * sizeof(int));
    u32* meta1 = (u32*)alloc(EE * sizeof(u32));
    u32* meta2 = (u32*)alloc(EE * sizeof(u32));
    int* cnt = (int*)alloc(NN * sizeof(int));
    int* cursor = (int*)alloc(NN * sizeof(int));
    int* chunk_sum = (int*)alloc(128 * sizeof(int));
    float* alpha = (float*)alloc(EE * sizeof(float));
    float* dinv1 = (float*)alloc(NN * sizeof(float));
    float* dinv2 = (float*)alloc(NN * sizeof(float));
    float* a_s = (float*)alloc(NN * sizeof(float));
    float* a_d = (float*)alloc(NN * sizeof(float));
    float* vs = (float*)alloc(HH * sizeof(float));
    float* vd = (float*)alloc(HH * sizeof(float));
    u16* Wt0 = (u16*)alloc(8192 * sizeof(u16));    // [128][64]
    u16* Wt1 = (u16*)alloc(16384 * sizeof(u16));   // [128][128]
    u16* Wt2 = (u16*)alloc(16384 * sizeof(u16));   // [128][128]
    u16* Wtr = (u16*)alloc(8192 * sizeof(u16));    // [64][128]
    u16* xb = (u16*)alloc((size_t)NN * FF * sizeof(u16));     // bf16(x)
    u16* xaggb = (u16*)alloc((size_t)NN * FF * sizeof(u16));  // bf16(Â x)
    u16* bufA = (u16*)alloc((size_t)NN * HH * sizeof(u16));
    u16* bufB = (u16*)alloc((size_t)NN * HH * sizeof(u16));

    hipMemsetAsync(cnt, 0, NN * sizeof(int), stream);

    // fused: edge count + x cast + weight transpose/cast + gemv
    build_k<<<(EE + PREP_ITEMS + 255) / 256, 256, 0, stream>>>(
        ecol, cnt, W0, W1, W2, Wr, Wg, att_src, att_dst, x,
        Wt0, Wt1, Wt2, Wtr, vs, vd, xb);
    chunksum_k<<<NCHUNK, 256, 0, stream>>>(cnt, chunk_sum, dinv1);
    colptr_k<<<NCHUNK, 256, 0, stream>>>(cnt, chunk_sum, col_ptr, cursor);
    fill_k<<<(EE + 255) / 256, 256, 0, stream>>>(erow, ecol, cursor, dinv1, meta1);

    int aggGrid = NN / 8;   // 12500, exact
    const int GG = 512;

    // layer 1: xagg = Â1 x ; y1 = relu(xagg@W0+b0)@W1 fused, + a_s/a_d
    aggx_k<<<aggGrid, 256, 0, stream>>>(xb, col_ptr, meta1, dinv1, xaggb);
    gemm1_k<<<GG, 256, 0, stream>>>(xaggb, Wt0, Wt1, b0, vs, vd, bufB, a_s, a_d);
    // attention
    attn_k<<<(NN + 31) / 32, 256, 0, stream>>>(col_ptr, meta1, a_s, a_d, alpha, dinv2);
    w2_k<<<(EE + 255) / 256, 256, 0, stream>>>(meta1, dinv2, alpha, meta2);
    // layer 2+3 fused: y2 = (relu-agg(y1)+b1)@W2
    agg_gemm_k<HH, false><<<NN / 8, 256, 0, stream>>>(bufB, col_ptr, meta2, dinv2, b1,
                                                      Wt2, nullptr, bufA);
    // layer 3+readout fused: out = (relu-agg(y2)+b2)@Wr + br
    agg_gemm_k<FF, true><<<NN / 8, 256, 0, stream>>>(bufA, col_ptr, meta2, dinv2, b2,
                                                     Wtr, br, out);
}

// Round 18
// 236.015 us; speedup vs baseline: 1.4418x; 1.1101x over previous
//
#include <hip/hip_runtime.h>
#include <hip/hip_bf16.h>
#include <hip/hip_fp16.h>
#include <math.h>

#define NN 100000
#define EE 600000
#define FF 64
#define HH 128
#define CHUNK 1024
#define NCHUNK ((NN + CHUNK - 1) / CHUNK)   // 98
#define NCHUNKS_M (NN / 16)                 // 6250 (exact)
#define PREP_ITEMS (NN * FF / 4 + 49280)

typedef unsigned short u16;
typedef unsigned int u32;
typedef __attribute__((ext_vector_type(8))) short bf16x8;
typedef __attribute__((ext_vector_type(4))) float f32x4;

__device__ __forceinline__ u16 f2bf(float f) {
    __hip_bfloat16 h = __float2bfloat16(f);
    return *(u16*)&h;
}
__device__ __forceinline__ float bf2f(u16 u) {
    unsigned int t = ((unsigned int)u) << 16;
    return *(float*)&t;
}
// meta pack: src in bits [31:15], fp16 weight (sign dropped, w>0) in [14:0]
__device__ __forceinline__ u32 enc_meta(int r, float w) {
    u16 hb = __half_as_ushort(__float2half(w));
    return ((u32)r << 15) | (hb & 0x7fffu);
}
__device__ __forceinline__ void dec_meta(u32 u, int& r, float& w) {
    r = (int)(u >> 15);
    w = __half2float(__ushort_as_half((u16)(u & 0x7fffu)));
}

// ---------------- fused: edge count (atomics) + weight/x prep ----------------

__global__ void build_k(const int* __restrict__ col, int* __restrict__ cnt,
                        const float* __restrict__ W0, const float* __restrict__ W1,
                        const float* __restrict__ W2, const float* __restrict__ Wr,
                        const float* __restrict__ Wg, const float* __restrict__ att_src,
                        const float* __restrict__ att_dst, const float* __restrict__ x,
                        u16* __restrict__ Wt0, u16* __restrict__ Wt1,
                        u16* __restrict__ Wt2, u16* __restrict__ Wtr,
                        float* __restrict__ vs, float* __restrict__ vd,
                        u16* __restrict__ xb) {
    int i = blockIdx.x * 256 + threadIdx.x;
    if (i < EE) {
        atomicAdd(&cnt[col[i]], 1);
        return;
    }
    i -= EE;
    if (i < NN * FF / 4) {          // cast x -> bf16
        float4 v = ((const float4*)x)[i];
        ushort4 o;
        o.x = f2bf(v.x); o.y = f2bf(v.y); o.z = f2bf(v.z); o.w = f2bf(v.w);
        ((ushort4*)xb)[i] = o;
        return;
    }
    i -= NN * FF / 4;
    if (i < 8192) {                 // Wt0: [128][64] from W0[64][128]
        int n = i >> 6, k = i & 63;
        Wt0[i] = f2bf(W0[k * 128 + n]);
        return;
    }
    i -= 8192;
    if (i < 16384) {                // Wt1: [128][128]
        int n = i >> 7, k = i & 127;
        Wt1[i] = f2bf(W1[k * 128 + n]);
        return;
    }
    i -= 16384;
    if (i < 16384) {                // Wt2: [128][128]
        int n = i >> 7, k = i & 127;
        Wt2[i] = f2bf(W2[k * 128 + n]);
        return;
    }
    i -= 16384;
    if (i < 8192) {                 // Wtr: [64][128] from Wr[128][64]
        int n = i >> 7, k = i & 127;
        Wtr[i] = f2bf(Wr[k * 64 + n]);
        return;
    }
    i -= 8192;
    if (i < HH) {                   // gemv: vs/vd = Wg @ att_{src,dst}
        float s1 = 0.f, s2 = 0.f;
        for (int j = 0; j < HH; j++) {
            float w = Wg[i * HH + j];
            s1 += w * att_src[j];
            s2 += w * att_dst[j];
        }
        vs[i] = s1;
        vd[i] = s2;
    }
}

// chunk sums + dinv1 fused
__global__ void chunksum_k(const int* __restrict__ cnt, int* __restrict__ chunk_sum,
                           float* __restrict__ dinv1) {
    int b = blockIdx.x, t = threadIdx.x;
    int base = b * CHUNK + t * 4;
    int s = 0;
    #pragma unroll
    for (int i = 0; i < 4; i++) {
        int idx = base + i;
        if (idx < NN) {
            int cv = cnt[idx];
            s += cv;
            dinv1[idx] = rsqrtf((float)cv + 1.0f);
        }
    }
    __shared__ int sm[4];
    for (int d = 32; d > 0; d >>= 1) s += __shfl_down(s, d);
    if ((t & 63) == 0) sm[t >> 6] = s;
    __syncthreads();
    if (t == 0) chunk_sum[b] = sm[0] + sm[1] + sm[2] + sm[3];
}

// col_ptr + cursor; chunk offset computed in-block (98 serial adds)
__global__ void colptr_k(const int* __restrict__ cnt, const int* __restrict__ chunk_sum,
                         int* __restrict__ col_ptr, int* __restrict__ cursor) {
    int b = blockIdx.x, t = threadIdx.x;
    __shared__ int base_off;
    if (t == 0) {
        int run = 0;
        for (int i = 0; i < b; i++) run += chunk_sum[i];
        base_off = run;
        if (b == 0) col_ptr[NN] = EE;
    }
    int base = b * CHUNK + t * 4;
    int c[4]; int tot = 0;
    #pragma unroll
    for (int i = 0; i < 4; i++) { int idx = base + i; c[i] = (idx < NN) ? cnt[idx] : 0; tot += c[i]; }
    __shared__ int s[256];
    s[t] = tot;
    __syncthreads();
    for (int d = 1; d < 256; d <<= 1) {
        int v = (t >= d) ? s[t - d] : 0;
        __syncthreads();
        s[t] += v;
        __syncthreads();
    }
    int excl = s[t] - tot;
    int off = base_off + excl;
    int pre = 0;
    #pragma unroll
    for (int i = 0; i < 4; i++) {
        int idx = base + i;
        if (idx < NN) {
            col_ptr[idx] = off + pre;
            cursor[idx] = off + pre;
        }
        pre += c[i];
    }
}

// fill CSR: single 4B scatter meta1 = enc(src, dinv1[r]*dinv1[c])
__global__ void fill_k(const int* __restrict__ row, const int* __restrict__ col,
                       int* __restrict__ cursor, const float* __restrict__ dinv1,
                       u32* __restrict__ meta1) {
    int e = blockIdx.x * 256 + threadIdx.x;
    if (e < EE) {
        int r = row[e], c = col[e];
        int slot = atomicAdd(&cursor[c], 1);
        meta1[slot] = enc_meta(r, dinv1[r] * dinv1[c]);
    }
}

// ---------------- layer-1 aggregate: 2 nodes/wave, 4 groups x 8 lanes x 2 streams ----------------

__global__ __launch_bounds__(256, 8) void aggx_k(
    const u16* __restrict__ xb, const int* __restrict__ col_ptr, const u32* __restrict__ meta1,
    const float* __restrict__ dinv1, u16* __restrict__ xout) {
    int wid = threadIdx.x >> 6, lane = threadIdx.x & 63;
    int sub = lane >> 5;
    int c = blockIdx.x * 8 + wid * 2 + sub;
    int hl = lane & 31;
    int g = hl >> 3;             // group 0..3
    int ch = (hl & 7) << 3;      // channel base 0,8,...,56
    int beg = col_ptr[c], end = col_ptr[c + 1];
    float acc[8] = {};

    int pA = beg + g, pB = pA + 4;
    int rA = 0, rB = 0; float wA = 0.f, wB = 0.f;
    if (pA < end) dec_meta(meta1[pA], rA, wA);
    if (pB < end) dec_meta(meta1[pB], rB, wB);
    while (pA < end) {
        bool hb = pB < end;
        bf16x8 vA = *(const bf16x8*)&xb[(size_t)rA * FF + ch];
        bf16x8 vB;
        if (hb) vB = *(const bf16x8*)&xb[(size_t)rB * FF + ch];
        int pA2 = pA + 8, pB2 = pB + 8;
        int rA2 = 0, rB2 = 0; float wA2 = 0.f, wB2 = 0.f;
        if (pA2 < end) dec_meta(meta1[pA2], rA2, wA2);
        if (pB2 < end) dec_meta(meta1[pB2], rB2, wB2);
        #pragma unroll
        for (int j = 0; j < 8; j++) acc[j] = fmaf(bf2f((u16)vA[j]), wA, acc[j]);
        if (hb) {
            #pragma unroll
            for (int j = 0; j < 8; j++) acc[j] = fmaf(bf2f((u16)vB[j]), wB, acc[j]);
        }
        pA = pA2; pB = pB2; rA = rA2; rB = rB2; wA = wA2; wB = wB2;
    }
    // combine 4 groups within half-wave (xor 8, 16)
    #pragma unroll
    for (int j = 0; j < 8; j++) {
        acc[j] += __shfl_xor(acc[j], 8);
        acc[j] += __shfl_xor(acc[j], 16);
    }

    if (g == 0) {
        bf16x8 v = *(const bf16x8*)&xb[(size_t)c * FF + ch];
        float dc = dinv1[c];
        float ws = dc * dc;
        bf16x8 o;
        #pragma unroll
        for (int j = 0; j < 8; j++) {
            float t = fmaf(bf2f((u16)v[j]), ws, acc[j]);
            o[j] = (short)f2bf(t);
        }
        *(bf16x8*)&xout[(size_t)c * FF + ch] = o;
    }
}

// ---------------- GEMM1 fused: y1 = (relu(xagg@W0+b0)) @ W1, plus a_s/a_d ----------------

__global__ __launch_bounds__(256) void gemm1_k(const u16* __restrict__ A,
                                               const u16* __restrict__ Wt0,
                                               const u16* __restrict__ Wt1,
                                               const float* __restrict__ bias,
                                               const float* __restrict__ vs, const float* __restrict__ vd,
                                               u16* __restrict__ Y, float* __restrict__ a_s,
                                               float* __restrict__ a_d) {
    constexpr int K = FF, N = HH, KK = K / 32, NT = N / 16, KK2 = HH / 32;
    constexpr int LSTRIDE = 136;
    __shared__ u16 lds[4][16 * LSTRIDE];
    int lane = threadIdx.x & 63, wid = threadIdx.x >> 6;
    int l15 = lane & 15, l4 = lane >> 4;
    int wg = blockIdx.x * 4 + wid;
    int nwaves = gridDim.x * 4;
    u16* myl = &lds[wid][0];

    bf16x8 a_frag[KK][NT];   // W0t fragments resident
    #pragma unroll
    for (int kk = 0; kk < KK; kk++)
        #pragma unroll
        for (int nt = 0; nt < NT; nt++)
            a_frag[kk][nt] = *(const bf16x8*)&Wt0[(size_t)(nt * 16 + l15) * K + kk * 32 + l4 * 8];

    for (int ch = wg; ch < NCHUNKS_M; ch += nwaves) {
        int row = ch * 16 + l15;
        bf16x8 b_frag[KK];
        #pragma unroll
        for (int kk = 0; kk < KK; kk++)
            b_frag[kk] = *(const bf16x8*)&A[(size_t)row * K + kk * 32 + l4 * 8];
        f32x4 acc[NT] = {};
        #pragma unroll
        for (int kk = 0; kk < KK; kk++)
            #pragma unroll
            for (int nt = 0; nt < NT; nt++)
                acc[nt] = __builtin_amdgcn_mfma_f32_16x16x32_bf16(a_frag[kk][nt], b_frag[kk],
                                                                  acc[nt], 0, 0, 0);
        float s1 = 0.f, s2 = 0.f;
        #pragma unroll
        for (int nt = 0; nt < NT; nt++) {
            f32x4 b4 = *(const f32x4*)&bias[nt * 16 + l4 * 4];
            f32x4 v4 = *(const f32x4*)&vs[nt * 16 + l4 * 4];
            f32x4 d4 = *(const f32x4*)&vd[nt * 16 + l4 * 4];
            float o0 = fmaxf(acc[nt][0] + b4[0], 0.f);
            float o1 = fmaxf(acc[nt][1] + b4[1], 0.f);
            float o2 = fmaxf(acc[nt][2] + b4[2], 0.f);
            float o3 = fmaxf(acc[nt][3] + b4[3], 0.f);
            ushort4 o;
            o.x = f2bf(o0); o.y = f2bf(o1); o.z = f2bf(o2); o.w = f2bf(o3);
            *(ushort4*)&myl[l15 * LSTRIDE + nt * 16 + l4 * 4] = o;
            s1 += o0 * v4[0] + o1 * v4[1] + o2 * v4[2] + o3 * v4[3];
            s2 += o0 * d4[0] + o1 * d4[1] + o2 * d4[2] + o3 * d4[3];
        }
        s1 += __shfl_xor(s1, 16); s1 += __shfl_xor(s1, 32);
        s2 += __shfl_xor(s2, 16); s2 += __shfl_xor(s2, 32);
        if (l4 == 0) {
            a_s[row] = s1;
            a_d[row] = s2;
        }
        // second GEMM: read x1 chunk back as B-fragments, multiply by W1t
        bf16x8 b2[KK2];
        #pragma unroll
        for (int kk2 = 0; kk2 < KK2; kk2++)
            b2[kk2] = *(const bf16x8*)&myl[l15 * LSTRIDE + kk2 * 32 + l4 * 8];
        f32x4 acc2[NT] = {};
        #pragma unroll
        for (int kk2 = 0; kk2 < KK2; kk2++)
            #pragma unroll
            for (int nt = 0; nt < NT; nt++) {
                bf16x8 w1f = *(const bf16x8*)&Wt1[(size_t)(nt * 16 + l15) * HH + kk2 * 32 + l4 * 8];
                acc2[nt] = __builtin_amdgcn_mfma_f32_16x16x32_bf16(w1f, b2[kk2], acc2[nt], 0, 0, 0);
            }
        #pragma unroll
        for (int nt = 0; nt < NT; nt++) {
            ushort4 o;
            o.x = f2bf(acc2[nt][0]);
            o.y = f2bf(acc2[nt][1]);
            o.z = f2bf(acc2[nt][2]);
            o.w = f2bf(acc2[nt][3]);
            *(ushort4*)&Y[(size_t)row * HH + nt * 16 + l4 * 4] = o;
        }
    }
}

// ---------------- attention: 8 lanes per node, online softmax ----------------

__global__ __launch_bounds__(256) void attn_k(const int* __restrict__ col_ptr,
                                              const u32* __restrict__ meta1,
                                              const float* __restrict__ a_s,
                                              const float* __restrict__ a_d,
                                              float* __restrict__ alpha,
                                              float* __restrict__ dinv2) {
    int lane = threadIdx.x & 63, wid = threadIdx.x >> 6;
    int grp = lane >> 3, idx = lane & 7;
    int c = blockIdx.x * 32 + wid * 8 + grp;
    if (c >= NN) return;
    int beg = col_ptr[c], end = col_ptr[c + 1];
    float ad = a_d[c];
    float es = a_s[c] + ad;
    es = (es > 0.f) ? es : 0.2f * es;
    float m = (idx == 0) ? es : -1e30f;
    float s = (idx == 0) ? 1.f : 0.f;
    for (int p = beg + idx; p < end; p += 8) {
        float e = a_s[meta1[p] >> 15] + ad;
        e = (e > 0.f) ? e : 0.2f * e;
        alpha[p] = e;
        float mn = fmaxf(m, e);
        s = s * expf(m - mn) + expf(e - mn);
        m = mn;
    }
    #pragma unroll
    for (int d = 1; d < 8; d <<= 1) {
        float mo = __shfl_xor(m, d);
        float so = __shfl_xor(s, d);
        float mn = fmaxf(m, mo);
        s = s * expf(m - mn) + so * expf(mo - mn);
        m = mn;
    }
    float inv = 1.f / s;
    float aself = expf(es - m) * inv;
    float d2 = rsqrtf(2.f - aself);
    if (idx == 0) dinv2[c] = d2;
    float sc = inv * d2;
    for (int p = beg + idx; p < end; p += 8)
        alpha[p] = expf(alpha[p] - m) * sc;
}

// meta2[p] = enc(src, alpha[p] * dinv2[src])
__global__ void w2_k(const u32* __restrict__ meta1, const float* __restrict__ dinv2,
                     const float* __restrict__ alpha, u32* __restrict__ meta2) {
    int p = blockIdx.x * 256 + threadIdx.x;
    if (p < EE) {
        u32 u = meta1[p];
        int r = (int)(u >> 15);
        float w = alpha[p] * dinv2[r];
        u16 hb = __half_as_ushort(__float2half(w));
        meta2[p] = (u & 0xffff8000u) | (hb & 0x7fffu);
    }
}

// ---------------- fused aggregate + GEMM (256 threads, 16 nodes, 4 named streams) ----------------
// Phase 1: 16 lanes/node, four named edge streams (stride 4) in flight; relu-agg
// rows land in a 16x136 LDS tile. Phase 2: wave wid computes n-tiles
// [wid*NT_W,(wid+1)*NT_W) of the 16x128 @ 128xNOUT MFMA GEMM.

template <int NOUT, bool OUTF32>
__global__ __launch_bounds__(256, 8) void agg_gemm_k(
    const u16* __restrict__ xw, const int* __restrict__ col_ptr, const u32* __restrict__ meta,
    const float* __restrict__ dinv2, const float* __restrict__ bias_in,
    const u16* __restrict__ Wt, const float* __restrict__ bias_out, void* __restrict__ Y_) {
    constexpr int KK2 = HH / 32;        // 4
    constexpr int NT = NOUT / 16;       // 8 or 4
    constexpr int NT_W = NT / 4;        // 2 or 1
    constexpr int LSTRIDE = 136;
    __shared__ u16 lds[16 * LSTRIDE];
    int tid = threadIdx.x;
    int lane = tid & 63, wid = tid >> 6;
    int node = tid >> 4;                // 0..15
    int ch = (tid & 15) << 3;           // channel base 0..120
    int cbase = blockIdx.x * 16;
    int c = cbase + node;
    int beg = col_ptr[c], end = col_ptr[c + 1];
    float acc[8] = {};

    // phase 1: four named streams, stride 4
    int pA = beg, pB = beg + 1, pC = beg + 2, pD = beg + 3;
    int rA = 0, rB = 0, rC = 0, rD = 0;
    float wA = 0.f, wB = 0.f, wC = 0.f, wD = 0.f;
    if (pA < end) dec_meta(meta[pA], rA, wA);
    if (pB < end) dec_meta(meta[pB], rB, wB);
    if (pC < end) dec_meta(meta[pC], rC, wC);
    if (pD < end) dec_meta(meta[pD], rD, wD);
    while (pA < end) {
        bool hb = pB < end, hc = pC < end, hd = pD < end;
        bf16x8 vA = *(const bf16x8*)&xw[(size_t)rA * HH + ch];
        bf16x8 vB, vC, vD;
        if (hb) vB = *(const bf16x8*)&xw[(size_t)rB * HH + ch];
        if (hc) vC = *(const bf16x8*)&xw[(size_t)rC * HH + ch];
        if (hd) vD = *(const bf16x8*)&xw[(size_t)rD * HH + ch];
        pA += 4; pB += 4; pC += 4; pD += 4;
        int rA2 = 0, rB2 = 0, rC2 = 0, rD2 = 0;
        float wA2 = 0.f, wB2 = 0.f, wC2 = 0.f, wD2 = 0.f;
        if (pA < end) dec_meta(meta[pA], rA2, wA2);
        if (pB < end) dec_meta(meta[pB], rB2, wB2);
        if (pC < end) dec_meta(meta[pC], rC2, wC2);
        if (pD < end) dec_meta(meta[pD], rD2, wD2);
        #pragma unroll
        for (int j = 0; j < 8; j++) acc[j] = fmaf(bf2f((u16)vA[j]), wA, acc[j]);
        if (hb) {
            #pragma unroll
            for (int j = 0; j < 8; j++) acc[j] = fmaf(bf2f((u16)vB[j]), wB, acc[j]);
        }
        if (hc) {
            #pragma unroll
            for (int j = 0; j < 8; j++) acc[j] = fmaf(bf2f((u16)vC[j]), wC, acc[j]);
        }
        if (hd) {
            #pragma unroll
            for (int j = 0; j < 8; j++) acc[j] = fmaf(bf2f((u16)vD[j]), wD, acc[j]);
        }
        rA = rA2; rB = rB2; rC = rC2; rD = rD2;
        wA = wA2; wB = wB2; wC = wC2; wD = wD2;
    }
    {   // self loop + bias_in + relu -> LDS row (bf16)
        bf16x8 v = *(const bf16x8*)&xw[(size_t)c * HH + ch];
        float dc = dinv2[c];
        float ws = dc * dc;
        f32x4 b4a = *(const f32x4*)&bias_in[ch];
        f32x4 b4b = *(const f32x4*)&bias_in[ch + 4];
        bf16x8 o;
        #pragma unroll
        for (int j = 0; j < 8; j++) {
            float bj = (j < 4) ? b4a[j] : b4b[j - 4];
            float t = fmaxf(fmaf(bf2f((u16)v[j]), ws, acc[j]) + bj, 0.f);
            o[j] = (short)f2bf(t);
        }
        *(bf16x8*)&lds[node * LSTRIDE + ch] = o;
    }
    __syncthreads();

    // phase 2: wave wid handles n-tiles [wid*NT_W, (wid+1)*NT_W)
    int l15 = lane & 15, l4 = lane >> 4;
    bf16x8 b2[KK2];
    #pragma unroll
    for (int kk2 = 0; kk2 < KK2; kk2++)
        b2[kk2] = *(const bf16x8*)&lds[l15 * LSTRIDE + kk2 * 32 + l4 * 8];
    int row = cbase + l15;
    #pragma unroll
    for (int ntw = 0; ntw < NT_W; ntw++) {
        int nt = wid * NT_W + ntw;
        f32x4 acc2 = {};
        #pragma unroll
        for (int kk2 = 0; kk2 < KK2; kk2++) {
            bf16x8 wf = *(const bf16x8*)&Wt[(size_t)(nt * 16 + l15) * HH + kk2 * 32 + l4 * 8];
            acc2 = __builtin_amdgcn_mfma_f32_16x16x32_bf16(wf, b2[kk2], acc2, 0, 0, 0);
        }
        int col = nt * 16 + l4 * 4;
        if (OUTF32) {
            float4 o;
            f32x4 bo = *(const f32x4*)&bias_out[col];
            o.x = acc2[0] + bo[0];
            o.y = acc2[1] + bo[1];
            o.z = acc2[2] + bo[2];
            o.w = acc2[3] + bo[3];
            *(float4*)&((float*)Y_)[(size_t)row * NOUT + col] = o;
        } else {
            ushort4 o;
            o.x = f2bf(acc2[0]);
            o.y = f2bf(acc2[1]);
            o.z = f2bf(acc2[2]);
            o.w = f2bf(acc2[3]);
            *(ushort4*)&((u16*)Y_)[(size_t)row * NOUT + col] = o;
        }
    }
}

// ---------------- launch ----------------

extern "C" void kernel_launch(void* const* d_in, const int* in_sizes, int n_in,
                              void* d_out, int out_size, void* d_ws, size_t ws_size,
                              hipStream_t stream) {
    const float* x = (const float*)d_in[0];
    const int* eidx = (const int*)d_in[1];     // [2][E]: row, col
    const float* W0 = (const float*)d_in[3];
    const float* b0 = (const float*)d_in[4];
    const float* Wg = (const float*)d_in[5];
    const float* att_src = (const float*)d_in[6];
    const float* att_dst = (const float*)d_in[7];
    const float* W1 = (const float*)d_in[8];
    const float* b1 = (const float*)d_in[9];
    const float* W2 = (const float*)d_in[10];
    const float* b2 = (const float*)d_in[11];
    const float* Wr = (const float*)d_in[12];
    const float* br = (const float*)d_in[13];
    float* out = (float*)d_out;

    const int* erow = eidx;
    const int* ecol = eidx + EE;

    char* p = (char*)d_ws;
    auto alloc = [&](size_t bytes) {
        void* r = (void*)p;
        p += (bytes + 255) & ~(size_t)255;
        return r;
    };
    int* col_ptr = (int*)alloc((NN + 1) * sizeof(int));
    u32* meta1 = (u32*)alloc(EE * sizeof(u32));
    u32* meta2 = (u32*)alloc(EE * sizeof(u32));
    int* cnt = (int*)alloc(NN * sizeof(int));
    int* cursor = (int*)alloc(NN * sizeof(int));
    int* chunk_sum = (int*)alloc(128 * sizeof(int));
    float* alpha = (float*)alloc(EE * sizeof(float));
    float* dinv1 = (float*)alloc(NN * sizeof(float));
    float* dinv2 = (float*)alloc(NN * sizeof(float));
    float* a_s = (float*)alloc(NN * sizeof(float));
    float* a_d = (float*)alloc(NN * sizeof(float));
    float* vs = (float*)alloc(HH * sizeof(float));
    float* vd = (float*)alloc(HH * sizeof(float));
    u16* Wt0 = (u16*)alloc(8192 * sizeof(u16));    // [128][64]
    u16* Wt1 = (u16*)alloc(16384 * sizeof(u16));   // [128][128]
    u16* Wt2 = (u16*)alloc(16384 * sizeof(u16));   // [128][128]
    u16* Wtr = (u16*)alloc(8192 * sizeof(u16));    // [64][128]
    u16* xb = (u16*)alloc((size_t)NN * FF * sizeof(u16));     // bf16(x)
    u16* xaggb = (u16*)alloc((size_t)NN * FF * sizeof(u16));  // bf16(Â x)
    u16* bufA = (u16*)alloc((size_t)NN * HH * sizeof(u16));
    u16* bufB = (u16*)alloc((size_t)NN * HH * sizeof(u16));

    hipMemsetAsync(cnt, 0, NN * sizeof(int), stream);

    // fused: edge count + x cast + weight transpose/cast + gemv
    build_k<<<(EE + PREP_ITEMS + 255) / 256, 256, 0, stream>>>(
        ecol, cnt, W0, W1, W2, Wr, Wg, att_src, att_dst, x,
        Wt0, Wt1, Wt2, Wtr, vs, vd, xb);
    chunksum_k<<<NCHUNK, 256, 0, stream>>>(cnt, chunk_sum, dinv1);
    colptr_k<<<NCHUNK, 256, 0, stream>>>(cnt, chunk_sum, col_ptr, cursor);
    fill_k<<<(EE + 255) / 256, 256, 0, stream>>>(erow, ecol, cursor, dinv1, meta1);

    int aggGrid = NN / 8;   // 12500, exact
    const int GG = 512;

    // layer 1: xagg = Â1 x ; y1 = relu(xagg@W0+b0)@W1 fused, + a_s/a_d
    aggx_k<<<aggGrid, 256, 0, stream>>>(xb, col_ptr, meta1, dinv1, xaggb);
    gemm1_k<<<GG, 256, 0, stream>>>(xaggb, Wt0, Wt1, b0, vs, vd, bufB, a_s, a_d);
    // attention
    attn_k<<<(NN + 31) / 32, 256, 0, stream>>>(col_ptr, meta1, a_s, a_d, alpha, dinv2);
    w2_k<<<(EE + 255) / 256, 256, 0, stream>>>(meta1, dinv2, alpha, meta2);
    // layer 2+3 fused: y2 = (relu-agg(y1)+b1)@W2
    agg_gemm_k<HH, false><<<NCHUNKS_M, 256, 0, stream>>>(bufB, col_ptr, meta2, dinv2, b1,
                                                         Wt2, nullptr, bufA);
    // layer 3+readout fused: out = (relu-agg(y2)+b2)@Wr + br
    agg_gemm_k<FF, true><<<NCHUNKS_M, 256, 0, stream>>>(bufA, col_ptr, meta2, dinv2, b2,
                                                        Wtr, br, out);
}